// Round 4
// baseline (290.556 us; speedup 1.0000x reference)
//
#include <hip/hip_runtime.h>
#include <math.h>

#define NN 100000   // nodes
#define NE 600000   // edges
#define DD 128      // hidden dim
#define NB_SCAN 98  // ceil(NN/1024)

// k_setup grid sections
#define NB_CAST 12500   // NN*32 float4s / 256
#define NB_PREPW 64     // 128*128 / 256
#define NB_DEG 2344     // ceil(NE/256)

typedef __attribute__((ext_vector_type(8))) short bf16x8;
typedef __attribute__((ext_vector_type(4))) float f32x4;
typedef unsigned short u16;
typedef unsigned int u32;

__device__ __forceinline__ float bflo(u32 w) {
    union { u32 i; float f; } v; v.i = w << 16; return v.f;
}
__device__ __forceinline__ float bfhi(u32 w) {
    union { u32 i; float f; } v; v.i = w & 0xffff0000u; return v.f;
}
__device__ __forceinline__ u16 f2bf(float f) {
    union { float f; u32 u; } v; v.f = f;
    u32 r = v.u + 0x7fffu + ((v.u >> 16) & 1u);  // RNE
    return (u16)(r >> 16);
}

// ---------------- setup: cast + weight prep + degree (after memset) --------

__global__ __launch_bounds__(256) void k_setup(const float* __restrict__ x,
                                               u16* __restrict__ xb,
                                               const float* __restrict__ Wl0,
                                               const float* __restrict__ Wr0,
                                               const float* __restrict__ Wl1,
                                               const float* __restrict__ Wr1,
                                               u16* __restrict__ Wc0,
                                               u16* __restrict__ Wc1,
                                               const int* __restrict__ dst,
                                               int* __restrict__ deg) {
    int b = blockIdx.x;
    int tid = threadIdx.x;
    if (b < NB_CAST) {
        int i = b * 256 + tid;               // float4 index, exact
        float4 v = reinterpret_cast<const float4*>(x)[i];
        ushort4 o;
        o.x = f2bf(v.x); o.y = f2bf(v.y); o.z = f2bf(v.z); o.w = f2bf(v.w);
        reinterpret_cast<ushort4*>(xb)[i] = o;
    } else if (b < NB_CAST + NB_PREPW) {
        int t = (b - NB_CAST) * 256 + tid;   // 0..16383, exact
        int j = t >> 7, k = t & 127;
        Wc0[j * 256 + k]       = f2bf(Wl0[t]);
        Wc0[j * 256 + 128 + k] = f2bf(Wr0[t]);
        Wc1[j * 256 + k]       = f2bf(Wl1[t]);
        Wc1[j * 256 + 128 + k] = f2bf(Wr1[t]);
    } else {
        int e = (b - NB_CAST - NB_PREPW) * 256 + tid;
        if (e < NE) atomicAdd(&deg[dst[e]], 1);
    }
}

// ---------------- CSR build ----------------

__global__ __launch_bounds__(256) void k_scan1(const int* __restrict__ deg,
                                               int* __restrict__ bsum) {
    __shared__ int sm[256];
    int t = threadIdx.x;
    int idx = blockIdx.x * 1024 + t * 4;
    int4 v = make_int4(0, 0, 0, 0);
    if (idx + 3 < NN) v = *reinterpret_cast<const int4*>(deg + idx);
    else {
        if (idx     < NN) v.x = deg[idx];
        if (idx + 1 < NN) v.y = deg[idx + 1];
        if (idx + 2 < NN) v.z = deg[idx + 2];
        if (idx + 3 < NN) v.w = deg[idx + 3];
    }
    sm[t] = v.x + v.y + v.z + v.w;
    __syncthreads();
    for (int off = 128; off > 0; off >>= 1) {
        if (t < off) sm[t] += sm[t + off];
        __syncthreads();
    }
    if (t == 0) bsum[blockIdx.x] = sm[0];
}

__global__ __launch_bounds__(128) void k_scan2(int* __restrict__ bsum) {
    __shared__ int sm[128];
    int t = threadIdx.x;
    int v = (t < NB_SCAN) ? bsum[t] : 0;
    sm[t] = v;
    __syncthreads();
    for (int off = 1; off < 128; off <<= 1) {
        int add = (t >= off) ? sm[t - off] : 0;
        __syncthreads();
        sm[t] += add;
        __syncthreads();
    }
    if (t < NB_SCAN) bsum[t] = (t == 0) ? 0 : sm[t - 1];  // exclusive, in-place
}

__global__ __launch_bounds__(256) void k_scan3(const int* __restrict__ deg,
                                               const int* __restrict__ boff,
                                               int* __restrict__ rp,
                                               int* __restrict__ cur,
                                               float* __restrict__ inv) {
    __shared__ int sm[256];
    int t = threadIdx.x;
    int idx = blockIdx.x * 1024 + t * 4;
    int4 v = make_int4(0, 0, 0, 0);
    if (idx + 3 < NN) v = *reinterpret_cast<const int4*>(deg + idx);
    else {
        if (idx     < NN) v.x = deg[idx];
        if (idx + 1 < NN) v.y = deg[idx + 1];
        if (idx + 2 < NN) v.z = deg[idx + 2];
        if (idx + 3 < NN) v.w = deg[idx + 3];
    }
    sm[t] = v.x + v.y + v.z + v.w;
    __syncthreads();
    for (int off = 1; off < 256; off <<= 1) {
        int add = (t >= off) ? sm[t - off] : 0;
        __syncthreads();
        sm[t] += add;
        __syncthreads();
    }
    int run = boff[blockIdx.x] + ((t == 0) ? 0 : sm[t - 1]);
    if (idx     < NN) { rp[idx]   = run; cur[idx]   = run; inv[idx]   = 1.0f / (float)(v.x > 0 ? v.x : 1); run += v.x; }
    if (idx + 1 < NN) { rp[idx+1] = run; cur[idx+1] = run; inv[idx+1] = 1.0f / (float)(v.y > 0 ? v.y : 1); run += v.y; }
    if (idx + 2 < NN) { rp[idx+2] = run; cur[idx+2] = run; inv[idx+2] = 1.0f / (float)(v.z > 0 ? v.z : 1); run += v.z; }
    if (idx + 3 < NN) { rp[idx+3] = run; cur[idx+3] = run; inv[idx+3] = 1.0f / (float)(v.w > 0 ? v.w : 1); run += v.w; }
    if (blockIdx.x == 0 && t == 0) rp[NN] = NE;
}

__global__ __launch_bounds__(256) void k_scatter(const int* __restrict__ src,
                                                 const int* __restrict__ dst,
                                                 int* __restrict__ cur,
                                                 int* __restrict__ col) {
    int e = blockIdx.x * 256 + threadIdx.x;
    if (e < NE) {
        int p = atomicAdd(&cur[dst[e]], 1);
        col[p] = src[e];
    }
}

// ---------------- aggregation (mean), bf16 ----------------
// 16 lanes per node; lane holds 16B (8 bf16) of the 256B row. 4-edge unroll.

__global__ __launch_bounds__(256) void k_gather128b(const u16* __restrict__ X,
                                                    const int* __restrict__ rp,
                                                    const int* __restrict__ col,
                                                    const float* __restrict__ inv,
                                                    u16* __restrict__ agg) {
    int tid = blockIdx.x * 256 + threadIdx.x;
    int n = tid >> 4;
    int sl = tid & 15;
    int beg = rp[n], end = rp[n + 1];
    float a0 = 0.f, a1 = 0.f, a2 = 0.f, a3 = 0.f, a4 = 0.f, a5 = 0.f, a6 = 0.f, a7 = 0.f;
    int e = beg;
    for (; e + 3 < end; e += 4) {
        int s0 = col[e], s1 = col[e + 1], s2 = col[e + 2], s3 = col[e + 3];
        uint4 v0 = *reinterpret_cast<const uint4*>(X + (size_t)s0 * DD + sl * 8);
        uint4 v1 = *reinterpret_cast<const uint4*>(X + (size_t)s1 * DD + sl * 8);
        uint4 v2 = *reinterpret_cast<const uint4*>(X + (size_t)s2 * DD + sl * 8);
        uint4 v3 = *reinterpret_cast<const uint4*>(X + (size_t)s3 * DD + sl * 8);
        a0 += (bflo(v0.x) + bflo(v1.x)) + (bflo(v2.x) + bflo(v3.x));
        a1 += (bfhi(v0.x) + bfhi(v1.x)) + (bfhi(v2.x) + bfhi(v3.x));
        a2 += (bflo(v0.y) + bflo(v1.y)) + (bflo(v2.y) + bflo(v3.y));
        a3 += (bfhi(v0.y) + bfhi(v1.y)) + (bfhi(v2.y) + bfhi(v3.y));
        a4 += (bflo(v0.z) + bflo(v1.z)) + (bflo(v2.z) + bflo(v3.z));
        a5 += (bfhi(v0.z) + bfhi(v1.z)) + (bfhi(v2.z) + bfhi(v3.z));
        a6 += (bflo(v0.w) + bflo(v1.w)) + (bflo(v2.w) + bflo(v3.w));
        a7 += (bfhi(v0.w) + bfhi(v1.w)) + (bfhi(v2.w) + bfhi(v3.w));
    }
    for (; e < end; ++e) {
        uint4 v0 = *reinterpret_cast<const uint4*>(X + (size_t)col[e] * DD + sl * 8);
        a0 += bflo(v0.x); a1 += bfhi(v0.x);
        a2 += bflo(v0.y); a3 += bfhi(v0.y);
        a4 += bflo(v0.z); a5 += bfhi(v0.z);
        a6 += bflo(v0.w); a7 += bfhi(v0.w);
    }
    float iv = inv[n];
    uint4 o;
    o.x = (u32)f2bf(a0 * iv) | ((u32)f2bf(a1 * iv) << 16);
    o.y = (u32)f2bf(a2 * iv) | ((u32)f2bf(a3 * iv) << 16);
    o.z = (u32)f2bf(a4 * iv) | ((u32)f2bf(a5 * iv) << 16);
    o.w = (u32)f2bf(a6 * iv) | ((u32)f2bf(a7 * iv) << 16);
    *reinterpret_cast<uint4*>(agg + (size_t)n * DD + sl * 8) = o;
}

// ---------------- MFMA fused epilogue (layers 0/1) ----------------
// out[n][j] = relu( [A0|A1][n][:] . Wc[j][:] + b[j] ),  K = 256, bf16 MFMA.
// No LDS, no barriers: W fragments read straight from global (64 KB,
// L2-resident, every 64B line fully consumed: 4 lanes x 16B). Each wave
// independently computes 32 nodes x 128 cols; node rows streamed to regs.
// Swapped operands: D row = W-row j, D col = node -> packed 8B stores.

__global__ __launch_bounds__(256) void k_mfma_epi(const u16* __restrict__ A0,
                                                  const u16* __restrict__ A1,
                                                  const u16* __restrict__ Wc,
                                                  const float* __restrict__ b,
                                                  u16* __restrict__ out,
                                                  int do_relu) {
    int tid = threadIdx.x;
    int wid = tid >> 6, lane = tid & 63;
    int n0 = blockIdx.x * 128 + wid * 32;
    if (n0 >= NN) return;
    int cl = lane & 15, rq = lane >> 4;

    f32x4 acc[2][8];
#pragma unroll
    for (int f = 0; f < 2; ++f)
#pragma unroll
        for (int jf = 0; jf < 8; ++jf) acc[f][jf] = (f32x4){0.f, 0.f, 0.f, 0.f};

    // W row for this lane's fragments: j = jf*16 + cl, k-slice rq*8 (u16 units)
    const u16* wbase = Wc + (size_t)cl * 256 + rq * 8;

    for (int half = 0; half < 2; ++half) {
        const u16* Ap = half ? A1 : A0;
        const u16* r0p = Ap + (size_t)(n0 + cl) * DD + rq * 8;
        const u16* r1p = Ap + (size_t)(n0 + 16 + cl) * DD + rq * 8;
        const u16* wp = wbase + half * 128;
#pragma unroll
        for (int ks = 0; ks < 4; ++ks) {
            bf16x8 x0 = *reinterpret_cast<const bf16x8*>(r0p + ks * 32);
            bf16x8 x1 = *reinterpret_cast<const bf16x8*>(r1p + ks * 32);
#pragma unroll
            for (int jf = 0; jf < 8; ++jf) {
                bf16x8 wf = *reinterpret_cast<const bf16x8*>(wp + ks * 32 + (size_t)jf * 16 * 256);
                acc[0][jf] = __builtin_amdgcn_mfma_f32_16x16x32_bf16(wf, x0, acc[0][jf], 0, 0, 0);
                acc[1][jf] = __builtin_amdgcn_mfma_f32_16x16x32_bf16(wf, x1, acc[1][jf], 0, 0, 0);
            }
        }
    }

    // epilogue: bias + relu + packed bf16x4 (8B) stores
#pragma unroll
    for (int jf = 0; jf < 8; ++jf) {
        float4 bias = *reinterpret_cast<const float4*>(b + jf * 16 + rq * 4);
#pragma unroll
        for (int f = 0; f < 2; ++f) {
            int n = n0 + f * 16 + cl;
            float o0 = acc[f][jf][0] + bias.x;
            float o1 = acc[f][jf][1] + bias.y;
            float o2 = acc[f][jf][2] + bias.z;
            float o3 = acc[f][jf][3] + bias.w;
            if (do_relu) {
                o0 = fmaxf(o0, 0.f); o1 = fmaxf(o1, 0.f);
                o2 = fmaxf(o2, 0.f); o3 = fmaxf(o3, 0.f);
            }
            uint2 pk;
            pk.x = (u32)f2bf(o0) | ((u32)f2bf(o1) << 16);
            pk.y = (u32)f2bf(o2) | ((u32)f2bf(o3) << 16);
            *reinterpret_cast<uint2*>(out + (size_t)n * DD + jf * 16 + rq * 4) = pk;
        }
    }
}

// ---------------- layer 2 ----------------

// hl2[n][j] = sum_k H[n][k] * Wl2[j][k]   (H bf16, W fp32 in LDS)
__global__ __launch_bounds__(256) void k_hl2(const u16* __restrict__ H,
                                             const float* __restrict__ Wl2,
                                             float* __restrict__ hl2) {
    __shared__ float Ws[16][128];
    int tid = threadIdx.x;
    for (int i = tid; i < 16 * 128; i += 256) Ws[i >> 7][i & 127] = Wl2[i];
    __syncthreads();
    int n = blockIdx.x * 256 + tid;
    if (n >= NN) return;
    const uint4* h4 = reinterpret_cast<const uint4*>(H + (size_t)n * DD);
    float acc[16];
#pragma unroll
    for (int j = 0; j < 16; ++j) acc[j] = 0.f;
    for (int c = 0; c < 16; ++c) {             // 8 bf16 per chunk
        uint4 hv = h4[c];
        float hf[8] = {bflo(hv.x), bfhi(hv.x), bflo(hv.y), bfhi(hv.y),
                       bflo(hv.z), bfhi(hv.z), bflo(hv.w), bfhi(hv.w)};
#pragma unroll
        for (int j = 0; j < 16; ++j) {
            const float4* w4 = reinterpret_cast<const float4*>(&Ws[j][c * 8]);
            float4 w0 = w4[0], w1 = w4[1];
            acc[j] += hf[0] * w0.x + hf[1] * w0.y + hf[2] * w0.z + hf[3] * w0.w
                    + hf[4] * w1.x + hf[5] * w1.y + hf[6] * w1.z + hf[7] * w1.w;
        }
    }
    float* dst = hl2 + (size_t)n * 16;
#pragma unroll
    for (int j4 = 0; j4 < 4; ++j4)
        *reinterpret_cast<float4*>(dst + j4 * 4) =
            make_float4(acc[j4 * 4], acc[j4 * 4 + 1], acc[j4 * 4 + 2], acc[j4 * 4 + 3]);
}

// fused: agg2 = mean-gather(hl2); out = log_softmax(agg2 + H@Wr2^T + b2)
__global__ __launch_bounds__(256) void k_l2_fused(const u16* __restrict__ H,
                                                  const float* __restrict__ hl2,
                                                  const int* __restrict__ rp,
                                                  const int* __restrict__ col,
                                                  const float* __restrict__ inv,
                                                  const float* __restrict__ Wr2,
                                                  const float* __restrict__ b2,
                                                  float* __restrict__ out) {
    __shared__ float Ws[16][128];
    __shared__ float bs[16];
    int tid = threadIdx.x;
    for (int i = tid; i < 16 * 128; i += 256) Ws[i >> 7][i & 127] = Wr2[i];
    if (tid < 16) bs[tid] = b2[tid];
    __syncthreads();
    int n = blockIdx.x * 256 + tid;
    if (n >= NN) return;

    // mean-gather of transformed neighbor features (16 floats per edge)
    float ag[16];
#pragma unroll
    for (int j = 0; j < 16; ++j) ag[j] = 0.f;
    int beg = rp[n], end = rp[n + 1];
    for (int e = beg; e < end; ++e) {
        const float4* r = reinterpret_cast<const float4*>(hl2 + (size_t)col[e] * 16);
        float4 q0 = r[0], q1 = r[1], q2 = r[2], q3 = r[3];
        ag[0] += q0.x; ag[1] += q0.y; ag[2]  += q0.z; ag[3]  += q0.w;
        ag[4] += q1.x; ag[5] += q1.y; ag[6]  += q1.z; ag[7]  += q1.w;
        ag[8] += q2.x; ag[9] += q2.y; ag[10] += q2.z; ag[11] += q2.w;
        ag[12] += q3.x; ag[13] += q3.y; ag[14] += q3.z; ag[15] += q3.w;
    }
    float iv = inv[n];

    // self transform: H[n] @ Wr2^T
    const uint4* h4 = reinterpret_cast<const uint4*>(H + (size_t)n * DD);
    float acc[16];
#pragma unroll
    for (int j = 0; j < 16; ++j) acc[j] = 0.f;
    for (int c = 0; c < 16; ++c) {
        uint4 hv = h4[c];
        float hf[8] = {bflo(hv.x), bfhi(hv.x), bflo(hv.y), bfhi(hv.y),
                       bflo(hv.z), bfhi(hv.z), bflo(hv.w), bfhi(hv.w)};
#pragma unroll
        for (int j = 0; j < 16; ++j) {
            const float4* w4 = reinterpret_cast<const float4*>(&Ws[j][c * 8]);
            float4 w0 = w4[0], w1 = w4[1];
            acc[j] += hf[0] * w0.x + hf[1] * w0.y + hf[2] * w0.z + hf[3] * w0.w
                    + hf[4] * w1.x + hf[5] * w1.y + hf[6] * w1.z + hf[7] * w1.w;
        }
    }

    float v[16];
    float m = -1e30f;
#pragma unroll
    for (int j = 0; j < 16; ++j) {
        v[j] = acc[j] + bs[j] + ag[j] * iv;
        m = fmaxf(m, v[j]);
    }
    float s = 0.f;
#pragma unroll
    for (int j = 0; j < 16; ++j) s += expf(v[j] - m);
    float lse = m + logf(s);
    float* dst = out + (size_t)n * 16;
#pragma unroll
    for (int j4 = 0; j4 < 4; ++j4)
        *reinterpret_cast<float4*>(dst + j4 * 4) =
            make_float4(v[j4 * 4] - lse, v[j4 * 4 + 1] - lse, v[j4 * 4 + 2] - lse, v[j4 * 4 + 3] - lse);
}

// ---------------- host launcher ----------------

extern "C" void kernel_launch(void* const* d_in, const int* in_sizes, int n_in,
                              void* d_out, int out_size, void* d_ws, size_t ws_size,
                              hipStream_t stream) {
    const float* x   = (const float*)d_in[0];
    const int*   ei  = (const int*)d_in[1];
    const float* Wl0 = (const float*)d_in[2];
    const float* bl0 = (const float*)d_in[3];
    const float* Wr0 = (const float*)d_in[4];
    const float* Wl1 = (const float*)d_in[5];
    const float* bl1 = (const float*)d_in[6];
    const float* Wr1 = (const float*)d_in[7];
    const float* Wl2 = (const float*)d_in[8];
    const float* bl2 = (const float*)d_in[9];
    const float* Wr2 = (const float*)d_in[10];
    float* out = (float*)d_out;

    const int* e_src = ei;       // edge_index[0]
    const int* e_dst = ei + NE;  // edge_index[1]

    // workspace carve-out (256B aligned)
    char* ws = (char*)d_ws;
    size_t off = 0;
    auto carve = [&](size_t bytes) -> void* {
        void* p = ws + off;
        off = (off + bytes + 255) & ~(size_t)255;
        return p;
    };
    int*   deg  = (int*)carve((size_t)NN * 4);
    int*   rp   = (int*)carve((size_t)(NN + 1) * 4);
    int*   cur  = (int*)carve((size_t)NN * 4);
    int*   bsum = (int*)carve(512 * 4);
    int*   col  = (int*)carve((size_t)NE * 4);
    float* inv  = (float*)carve((size_t)NN * 4);
    u16*   xb   = (u16*)carve((size_t)NN * DD * 2);
    u16*   aggb = (u16*)carve((size_t)NN * DD * 2);
    u16*   Hb   = (u16*)carve((size_t)NN * DD * 2);
    u16*   Wc0  = (u16*)carve((size_t)128 * 256 * 2);
    u16*   Wc1  = (u16*)carve((size_t)128 * 256 * 2);
    float* hl2  = (float*)carve((size_t)NN * 16 * 4);
    (void)ws_size; (void)in_sizes; (void)n_in; (void)out_size;

    // setup: zero degree, then {cast | weight-prep | degree-count}
    hipMemsetAsync(deg, 0, (size_t)NN * 4, stream);
    k_setup<<<NB_CAST + NB_PREPW + NB_DEG, 256, 0, stream>>>(
        x, xb, Wl0, Wr0, Wl1, Wr1, Wc0, Wc1, e_dst, deg);

    // CSR build
    k_scan1<<<NB_SCAN, 256, 0, stream>>>(deg, bsum);
    k_scan2<<<1, 128, 0, stream>>>(bsum);
    k_scan3<<<NB_SCAN, 256, 0, stream>>>(deg, bsum, rp, cur, inv);
    k_scatter<<<(NE + 255) / 256, 256, 0, stream>>>(e_src, e_dst, cur, col);

    const int nblk = (NN + 127) / 128;  // 782

    // layer 0: aggb = mean-gather(xb); Hb = relu([aggb|xb]@Wc0 + bl0)
    k_gather128b<<<NN / 16, 256, 0, stream>>>(xb, rp, col, inv, aggb);
    k_mfma_epi<<<nblk, 256, 0, stream>>>(aggb, xb, Wc0, bl0, Hb, 1);

    // layer 1 (in-place on Hb: each wave reads exactly the rows it writes)
    k_gather128b<<<NN / 16, 256, 0, stream>>>(Hb, rp, col, inv, aggb);
    k_mfma_epi<<<nblk, 256, 0, stream>>>(aggb, Hb, Wc1, bl1, Hb, 1);

    // layer 2: transform-first, then fused {16-wide gather + log_softmax}
    k_hl2<<<(NN + 255) / 256, 256, 0, stream>>>(Hb, Wl2, hl2);
    k_l2_fused<<<(NN + 255) / 256, 256, 0, stream>>>(Hb, hl2, rp, col, inv, Wr2, bl2, out);
}

// Round 5
// 281.460 us; speedup vs baseline: 1.0323x; 1.0323x over previous
//
#include <hip/hip_runtime.h>
#include <math.h>

#define NN 100000   // nodes
#define NE 600000   // edges
#define DD 128      // hidden dim
#define NB_SCAN 98  // ceil(NN/1024)

// k_setup grid sections
#define NB_CAST 12500   // NN*32 float4s / 256
#define NB_PREPW 64     // 128*128 / 256
#define NB_DEG 2344     // ceil(NE/256)

typedef __attribute__((ext_vector_type(8))) short bf16x8;
typedef __attribute__((ext_vector_type(4))) float f32x4;
typedef unsigned short u16;
typedef unsigned int u32;

__device__ __forceinline__ float bflo(u32 w) {
    union { u32 i; float f; } v; v.i = w << 16; return v.f;
}
__device__ __forceinline__ float bfhi(u32 w) {
    union { u32 i; float f; } v; v.i = w & 0xffff0000u; return v.f;
}
__device__ __forceinline__ u16 f2bf(float f) {
    union { float f; u32 u; } v; v.f = f;
    u32 r = v.u + 0x7fffu + ((v.u >> 16) & 1u);  // RNE
    return (u16)(r >> 16);
}

// ---------------- setup: cast + weight prep + degree (after memset) --------

__global__ __launch_bounds__(256) void k_setup(const float* __restrict__ x,
                                               u16* __restrict__ xb,
                                               const float* __restrict__ Wl0,
                                               const float* __restrict__ Wr0,
                                               const float* __restrict__ Wl1,
                                               const float* __restrict__ Wr1,
                                               u16* __restrict__ Wc0,
                                               u16* __restrict__ Wc1,
                                               const int* __restrict__ dst,
                                               int* __restrict__ deg) {
    int b = blockIdx.x;
    int tid = threadIdx.x;
    if (b < NB_CAST) {
        int i = b * 256 + tid;               // float4 index, exact
        float4 v = reinterpret_cast<const float4*>(x)[i];
        ushort4 o;
        o.x = f2bf(v.x); o.y = f2bf(v.y); o.z = f2bf(v.z); o.w = f2bf(v.w);
        reinterpret_cast<ushort4*>(xb)[i] = o;
    } else if (b < NB_CAST + NB_PREPW) {
        int t = (b - NB_CAST) * 256 + tid;   // 0..16383, exact
        int j = t >> 7, k = t & 127;
        Wc0[j * 256 + k]       = f2bf(Wl0[t]);
        Wc0[j * 256 + 128 + k] = f2bf(Wr0[t]);
        Wc1[j * 256 + k]       = f2bf(Wl1[t]);
        Wc1[j * 256 + 128 + k] = f2bf(Wr1[t]);
    } else {
        int e = (b - NB_CAST - NB_PREPW) * 256 + tid;
        if (e < NE) atomicAdd(&deg[dst[e]], 1);
    }
}

// ---------------- CSR build ----------------

__global__ __launch_bounds__(256) void k_scan1(const int* __restrict__ deg,
                                               int* __restrict__ bsum) {
    __shared__ int sm[256];
    int t = threadIdx.x;
    int idx = blockIdx.x * 1024 + t * 4;
    int4 v = make_int4(0, 0, 0, 0);
    if (idx + 3 < NN) v = *reinterpret_cast<const int4*>(deg + idx);
    else {
        if (idx     < NN) v.x = deg[idx];
        if (idx + 1 < NN) v.y = deg[idx + 1];
        if (idx + 2 < NN) v.z = deg[idx + 2];
        if (idx + 3 < NN) v.w = deg[idx + 3];
    }
    sm[t] = v.x + v.y + v.z + v.w;
    __syncthreads();
    for (int off = 128; off > 0; off >>= 1) {
        if (t < off) sm[t] += sm[t + off];
        __syncthreads();
    }
    if (t == 0) bsum[blockIdx.x] = sm[0];
}

__global__ __launch_bounds__(128) void k_scan2(int* __restrict__ bsum) {
    __shared__ int sm[128];
    int t = threadIdx.x;
    int v = (t < NB_SCAN) ? bsum[t] : 0;
    sm[t] = v;
    __syncthreads();
    for (int off = 1; off < 128; off <<= 1) {
        int add = (t >= off) ? sm[t - off] : 0;
        __syncthreads();
        sm[t] += add;
        __syncthreads();
    }
    if (t < NB_SCAN) bsum[t] = (t == 0) ? 0 : sm[t - 1];  // exclusive, in-place
}

__global__ __launch_bounds__(256) void k_scan3(const int* __restrict__ deg,
                                               const int* __restrict__ boff,
                                               int* __restrict__ rp,
                                               int* __restrict__ cur,
                                               float* __restrict__ inv) {
    __shared__ int sm[256];
    int t = threadIdx.x;
    int idx = blockIdx.x * 1024 + t * 4;
    int4 v = make_int4(0, 0, 0, 0);
    if (idx + 3 < NN) v = *reinterpret_cast<const int4*>(deg + idx);
    else {
        if (idx     < NN) v.x = deg[idx];
        if (idx + 1 < NN) v.y = deg[idx + 1];
        if (idx + 2 < NN) v.z = deg[idx + 2];
        if (idx + 3 < NN) v.w = deg[idx + 3];
    }
    sm[t] = v.x + v.y + v.z + v.w;
    __syncthreads();
    for (int off = 1; off < 256; off <<= 1) {
        int add = (t >= off) ? sm[t - off] : 0;
        __syncthreads();
        sm[t] += add;
        __syncthreads();
    }
    int run = boff[blockIdx.x] + ((t == 0) ? 0 : sm[t - 1]);
    if (idx     < NN) { rp[idx]   = run; cur[idx]   = run; inv[idx]   = 1.0f / (float)(v.x > 0 ? v.x : 1); run += v.x; }
    if (idx + 1 < NN) { rp[idx+1] = run; cur[idx+1] = run; inv[idx+1] = 1.0f / (float)(v.y > 0 ? v.y : 1); run += v.y; }
    if (idx + 2 < NN) { rp[idx+2] = run; cur[idx+2] = run; inv[idx+2] = 1.0f / (float)(v.z > 0 ? v.z : 1); run += v.z; }
    if (idx + 3 < NN) { rp[idx+3] = run; cur[idx+3] = run; inv[idx+3] = 1.0f / (float)(v.w > 0 ? v.w : 1); run += v.w; }
    if (blockIdx.x == 0 && t == 0) rp[NN] = NE;
}

__global__ __launch_bounds__(256) void k_scatter(const int* __restrict__ src,
                                                 const int* __restrict__ dst,
                                                 int* __restrict__ cur,
                                                 int* __restrict__ col) {
    int e = blockIdx.x * 256 + threadIdx.x;
    if (e < NE) {
        int p = atomicAdd(&cur[dst[e]], 1);
        col[p] = src[e];
    }
}

// ---------------- fused SAGE layer (layers 0/1) ----------------
// One block = 16 nodes.  Phase 1: mean-gather X rows (16 lanes/node) into
// registers -> bf16 -> LDS [agg|x] K=256 (XOR-swizzled). Phase 2: each wave
// computes 16 nodes x 32 cols: B-frags from LDS, W-frags (A) from global
// (64 KB, L2-hot), 16 MFMAs, bias+relu, packed 8B stores.
// out[n][j] = relu( [agg|x][n][:] . Wc[j][:] + b[j] )

__global__ __launch_bounds__(256) void k_fused_layer(const u16* __restrict__ X,
                                                     const int* __restrict__ rp,
                                                     const int* __restrict__ col,
                                                     const float* __restrict__ inv,
                                                     const u16* __restrict__ Wc,
                                                     const float* __restrict__ b,
                                                     u16* __restrict__ out) {
    __shared__ u16 XK[16 * 256];  // 8 KB; row = local node (512 B), swizzle: byte ^ (nl&7)<<4
    char* lds = reinterpret_cast<char*>(XK);

    int tid = threadIdx.x;
    int nl = tid >> 4;     // local node 0..15
    int sl = tid & 15;     // 16B k-slice 0..15
    int n = blockIdx.x * 16 + nl;

    // self row -> LDS (K = 128 + sl*8), independent of gather
    uint4 xv = *reinterpret_cast<const uint4*>(X + (size_t)n * DD + sl * 8);
    *reinterpret_cast<uint4*>(lds + nl * 512 + ((256 + sl * 16) ^ ((nl & 7) << 4))) = xv;

    // mean-gather
    int beg = rp[n], end = rp[n + 1];
    float a0 = 0.f, a1 = 0.f, a2 = 0.f, a3 = 0.f, a4 = 0.f, a5 = 0.f, a6 = 0.f, a7 = 0.f;
    int e = beg;
    for (; e + 3 < end; e += 4) {
        int s0 = col[e], s1 = col[e + 1], s2 = col[e + 2], s3 = col[e + 3];
        uint4 v0 = *reinterpret_cast<const uint4*>(X + (size_t)s0 * DD + sl * 8);
        uint4 v1 = *reinterpret_cast<const uint4*>(X + (size_t)s1 * DD + sl * 8);
        uint4 v2 = *reinterpret_cast<const uint4*>(X + (size_t)s2 * DD + sl * 8);
        uint4 v3 = *reinterpret_cast<const uint4*>(X + (size_t)s3 * DD + sl * 8);
        a0 += (bflo(v0.x) + bflo(v1.x)) + (bflo(v2.x) + bflo(v3.x));
        a1 += (bfhi(v0.x) + bfhi(v1.x)) + (bfhi(v2.x) + bfhi(v3.x));
        a2 += (bflo(v0.y) + bflo(v1.y)) + (bflo(v2.y) + bflo(v3.y));
        a3 += (bfhi(v0.y) + bfhi(v1.y)) + (bfhi(v2.y) + bfhi(v3.y));
        a4 += (bflo(v0.z) + bflo(v1.z)) + (bflo(v2.z) + bflo(v3.z));
        a5 += (bfhi(v0.z) + bfhi(v1.z)) + (bfhi(v2.z) + bfhi(v3.z));
        a6 += (bflo(v0.w) + bflo(v1.w)) + (bflo(v2.w) + bflo(v3.w));
        a7 += (bfhi(v0.w) + bfhi(v1.w)) + (bfhi(v2.w) + bfhi(v3.w));
    }
    for (; e < end; ++e) {
        uint4 v0 = *reinterpret_cast<const uint4*>(X + (size_t)col[e] * DD + sl * 8);
        a0 += bflo(v0.x); a1 += bfhi(v0.x);
        a2 += bflo(v0.y); a3 += bfhi(v0.y);
        a4 += bflo(v0.z); a5 += bfhi(v0.z);
        a6 += bflo(v0.w); a7 += bfhi(v0.w);
    }
    float iv = inv[n];
    uint4 o;
    o.x = (u32)f2bf(a0 * iv) | ((u32)f2bf(a1 * iv) << 16);
    o.y = (u32)f2bf(a2 * iv) | ((u32)f2bf(a3 * iv) << 16);
    o.z = (u32)f2bf(a4 * iv) | ((u32)f2bf(a5 * iv) << 16);
    o.w = (u32)f2bf(a6 * iv) | ((u32)f2bf(a7 * iv) << 16);
    *reinterpret_cast<uint4*>(lds + nl * 512 + ((sl * 16) ^ ((nl & 7) << 4))) = o;
    __syncthreads();

    // ---- phase 2: GEMM ----
    int wid = tid >> 6, lane = tid & 63;
    int cl = lane & 15, rq = lane >> 4;

    f32x4 acc0 = (f32x4){0.f, 0.f, 0.f, 0.f};
    f32x4 acc1 = (f32x4){0.f, 0.f, 0.f, 0.f};
    const u16* wbase = Wc + (size_t)(wid * 32 + cl) * 256 + rq * 8;
    const char* xbase = lds + cl * 512;
    int xmask = (cl & 7) << 4;
#pragma unroll
    for (int ks = 0; ks < 8; ++ks) {
        bf16x8 xf = *reinterpret_cast<const bf16x8*>(xbase + ((ks * 64 + rq * 16) ^ xmask));
        bf16x8 w0 = *reinterpret_cast<const bf16x8*>(wbase + ks * 32);
        bf16x8 w1 = *reinterpret_cast<const bf16x8*>(wbase + 16 * 256 + ks * 32);
        acc0 = __builtin_amdgcn_mfma_f32_16x16x32_bf16(w0, xf, acc0, 0, 0, 0);
        acc1 = __builtin_amdgcn_mfma_f32_16x16x32_bf16(w1, xf, acc1, 0, 0, 0);
    }

    // epilogue: lane holds node (blk*16+cl), cols j = wid*32 + jf*16 + rq*4 + v
    int nout = blockIdx.x * 16 + cl;
    u16* orow = out + (size_t)nout * DD + wid * 32 + rq * 4;
#pragma unroll
    for (int jf = 0; jf < 2; ++jf) {
        f32x4 a = jf ? acc1 : acc0;
        float4 bias = *reinterpret_cast<const float4*>(b + wid * 32 + jf * 16 + rq * 4);
        float o0 = fmaxf(a[0] + bias.x, 0.f);
        float o1 = fmaxf(a[1] + bias.y, 0.f);
        float o2 = fmaxf(a[2] + bias.z, 0.f);
        float o3 = fmaxf(a[3] + bias.w, 0.f);
        uint2 pk;
        pk.x = (u32)f2bf(o0) | ((u32)f2bf(o1) << 16);
        pk.y = (u32)f2bf(o2) | ((u32)f2bf(o3) << 16);
        *reinterpret_cast<uint2*>(orow + jf * 16) = pk;
    }
}

// ---------------- layer 2 ----------------

// hl2[n][j] = sum_k H[n][k] * Wl2[j][k]   (H bf16, W fp32 in LDS)
__global__ __launch_bounds__(256) void k_hl2(const u16* __restrict__ H,
                                             const float* __restrict__ Wl2,
                                             float* __restrict__ hl2) {
    __shared__ float Ws[16][128];
    int tid = threadIdx.x;
    for (int i = tid; i < 16 * 128; i += 256) Ws[i >> 7][i & 127] = Wl2[i];
    __syncthreads();
    int n = blockIdx.x * 256 + tid;
    if (n >= NN) return;
    const uint4* h4 = reinterpret_cast<const uint4*>(H + (size_t)n * DD);
    float acc[16];
#pragma unroll
    for (int j = 0; j < 16; ++j) acc[j] = 0.f;
    for (int c = 0; c < 16; ++c) {             // 8 bf16 per chunk
        uint4 hv = h4[c];
        float hf[8] = {bflo(hv.x), bfhi(hv.x), bflo(hv.y), bfhi(hv.y),
                       bflo(hv.z), bfhi(hv.z), bflo(hv.w), bfhi(hv.w)};
#pragma unroll
        for (int j = 0; j < 16; ++j) {
            const float4* w4 = reinterpret_cast<const float4*>(&Ws[j][c * 8]);
            float4 w0 = w4[0], w1 = w4[1];
            acc[j] += hf[0] * w0.x + hf[1] * w0.y + hf[2] * w0.z + hf[3] * w0.w
                    + hf[4] * w1.x + hf[5] * w1.y + hf[6] * w1.z + hf[7] * w1.w;
        }
    }
    float* dst = hl2 + (size_t)n * 16;
#pragma unroll
    for (int j4 = 0; j4 < 4; ++j4)
        *reinterpret_cast<float4*>(dst + j4 * 4) =
            make_float4(acc[j4 * 4], acc[j4 * 4 + 1], acc[j4 * 4 + 2], acc[j4 * 4 + 3]);
}

// fused: agg2 = mean-gather(hl2); out = log_softmax(agg2 + H@Wr2^T + b2)
__global__ __launch_bounds__(256) void k_l2_fused(const u16* __restrict__ H,
                                                  const float* __restrict__ hl2,
                                                  const int* __restrict__ rp,
                                                  const int* __restrict__ col,
                                                  const float* __restrict__ inv,
                                                  const float* __restrict__ Wr2,
                                                  const float* __restrict__ b2,
                                                  float* __restrict__ out) {
    __shared__ float Ws[16][128];
    __shared__ float bs[16];
    int tid = threadIdx.x;
    for (int i = tid; i < 16 * 128; i += 256) Ws[i >> 7][i & 127] = Wr2[i];
    if (tid < 16) bs[tid] = b2[tid];
    __syncthreads();
    int n = blockIdx.x * 256 + tid;
    if (n >= NN) return;

    // mean-gather of transformed neighbor features (16 floats per edge)
    float ag[16];
#pragma unroll
    for (int j = 0; j < 16; ++j) ag[j] = 0.f;
    int beg = rp[n], end = rp[n + 1];
    for (int e = beg; e < end; ++e) {
        const float4* r = reinterpret_cast<const float4*>(hl2 + (size_t)col[e] * 16);
        float4 q0 = r[0], q1 = r[1], q2 = r[2], q3 = r[3];
        ag[0] += q0.x; ag[1] += q0.y; ag[2]  += q0.z; ag[3]  += q0.w;
        ag[4] += q1.x; ag[5] += q1.y; ag[6]  += q1.z; ag[7]  += q1.w;
        ag[8] += q2.x; ag[9] += q2.y; ag[10] += q2.z; ag[11] += q2.w;
        ag[12] += q3.x; ag[13] += q3.y; ag[14] += q3.z; ag[15] += q3.w;
    }
    float iv = inv[n];

    // self transform: H[n] @ Wr2^T
    const uint4* h4 = reinterpret_cast<const uint4*>(H + (size_t)n * DD);
    float acc[16];
#pragma unroll
    for (int j = 0; j < 16; ++j) acc[j] = 0.f;
    for (int c = 0; c < 16; ++c) {
        uint4 hv = h4[c];
        float hf[8] = {bflo(hv.x), bfhi(hv.x), bflo(hv.y), bfhi(hv.y),
                       bflo(hv.z), bfhi(hv.z), bflo(hv.w), bfhi(hv.w)};
#pragma unroll
        for (int j = 0; j < 16; ++j) {
            const float4* w4 = reinterpret_cast<const float4*>(&Ws[j][c * 8]);
            float4 w0 = w4[0], w1 = w4[1];
            acc[j] += hf[0] * w0.x + hf[1] * w0.y + hf[2] * w0.z + hf[3] * w0.w
                    + hf[4] * w1.x + hf[5] * w1.y + hf[6] * w1.z + hf[7] * w1.w;
        }
    }

    float v[16];
    float m = -1e30f;
#pragma unroll
    for (int j = 0; j < 16; ++j) {
        v[j] = acc[j] + bs[j] + ag[j] * iv;
        m = fmaxf(m, v[j]);
    }
    float s = 0.f;
#pragma unroll
    for (int j = 0; j < 16; ++j) s += expf(v[j] - m);
    float lse = m + logf(s);
    float* dst = out + (size_t)n * 16;
#pragma unroll
    for (int j4 = 0; j4 < 4; ++j4)
        *reinterpret_cast<float4*>(dst + j4 * 4) =
            make_float4(v[j4 * 4] - lse, v[j4 * 4 + 1] - lse, v[j4 * 4 + 2] - lse, v[j4 * 4 + 3] - lse);
}

// ---------------- host launcher ----------------

extern "C" void kernel_launch(void* const* d_in, const int* in_sizes, int n_in,
                              void* d_out, int out_size, void* d_ws, size_t ws_size,
                              hipStream_t stream) {
    const float* x   = (const float*)d_in[0];
    const int*   ei  = (const int*)d_in[1];
    const float* Wl0 = (const float*)d_in[2];
    const float* bl0 = (const float*)d_in[3];
    const float* Wr0 = (const float*)d_in[4];
    const float* Wl1 = (const float*)d_in[5];
    const float* bl1 = (const float*)d_in[6];
    const float* Wr1 = (const float*)d_in[7];
    const float* Wl2 = (const float*)d_in[8];
    const float* bl2 = (const float*)d_in[9];
    const float* Wr2 = (const float*)d_in[10];
    float* out = (float*)d_out;

    const int* e_src = ei;       // edge_index[0]
    const int* e_dst = ei + NE;  // edge_index[1]

    // workspace carve-out (256B aligned)
    char* ws = (char*)d_ws;
    size_t off = 0;
    auto carve = [&](size_t bytes) -> void* {
        void* p = ws + off;
        off = (off + bytes + 255) & ~(size_t)255;
        return p;
    };
    int*   deg  = (int*)carve((size_t)NN * 4);
    int*   rp   = (int*)carve((size_t)(NN + 1) * 4);
    int*   cur  = (int*)carve((size_t)NN * 4);
    int*   bsum = (int*)carve(512 * 4);
    int*   col  = (int*)carve((size_t)NE * 4);
    float* inv  = (float*)carve((size_t)NN * 4);
    u16*   xb   = (u16*)carve((size_t)NN * DD * 2);
    u16*   H1   = (u16*)carve((size_t)NN * DD * 2);
    u16*   H2   = (u16*)carve((size_t)NN * DD * 2);
    u16*   Wc0  = (u16*)carve((size_t)128 * 256 * 2);
    u16*   Wc1  = (u16*)carve((size_t)128 * 256 * 2);
    float* hl2  = (float*)carve((size_t)NN * 16 * 4);
    (void)ws_size; (void)in_sizes; (void)n_in; (void)out_size;

    // setup: zero degree, then {cast | weight-prep | degree-count}
    hipMemsetAsync(deg, 0, (size_t)NN * 4, stream);
    k_setup<<<NB_CAST + NB_PREPW + NB_DEG, 256, 0, stream>>>(
        x, xb, Wl0, Wr0, Wl1, Wr1, Wc0, Wc1, e_dst, deg);

    // CSR build
    k_scan1<<<NB_SCAN, 256, 0, stream>>>(deg, bsum);
    k_scan2<<<1, 128, 0, stream>>>(bsum);
    k_scan3<<<NB_SCAN, 256, 0, stream>>>(deg, bsum, rp, cur, inv);
    k_scatter<<<(NE + 255) / 256, 256, 0, stream>>>(e_src, e_dst, cur, col);

    // layer 0: H1 = relu([mean-gather(xb) | xb] @ Wc0 + bl0)   (fused)
    k_fused_layer<<<NN / 16, 256, 0, stream>>>(xb, rp, col, inv, Wc0, bl0, H1);

    // layer 1: H2 = relu([mean-gather(H1) | H1] @ Wc1 + bl1)   (fused)
    k_fused_layer<<<NN / 16, 256, 0, stream>>>(H1, rp, col, inv, Wc1, bl1, H2);

    // layer 2: transform-first, then fused {16-wide gather + log_softmax}
    k_hl2<<<(NN + 255) / 256, 256, 0, stream>>>(H2, Wl2, hl2);
    k_l2_fused<<<(NN + 255) / 256, 256, 0, stream>>>(H2, hl2, rp, col, inv, Wr2, bl2, out);
}

// Round 6
// 277.479 us; speedup vs baseline: 1.0471x; 1.0143x over previous
//
#include <hip/hip_runtime.h>
#include <math.h>

#define NN 100000   // nodes
#define NE 600000   // edges
#define DD 128      // hidden dim
#define NB_SCAN 98  // ceil(NN/1024)

// k_setup grid sections
#define NB_CAST 12500   // NN*32 float4s / 256
#define NB_PREPW 64     // 128*128 / 256
#define NB_DEG 2344     // ceil(NE/256)

typedef __attribute__((ext_vector_type(8))) short bf16x8;
typedef __attribute__((ext_vector_type(4))) float f32x4;
typedef unsigned short u16;
typedef unsigned int u32;

__device__ __forceinline__ float bflo(u32 w) {
    union { u32 i; float f; } v; v.i = w << 16; return v.f;
}
__device__ __forceinline__ float bfhi(u32 w) {
    union { u32 i; float f; } v; v.i = w & 0xffff0000u; return v.f;
}
__device__ __forceinline__ u16 f2bf(float f) {
    union { float f; u32 u; } v; v.f = f;
    u32 r = v.u + 0x7fffu + ((v.u >> 16) & 1u);  // RNE
    return (u16)(r >> 16);
}

// ---------------- setup: cast + weight prep + degree + zero-rows ----------

__global__ __launch_bounds__(256) void k_setup(const float* __restrict__ x,
                                               u16* __restrict__ xb,
                                               const float* __restrict__ Wl0,
                                               const float* __restrict__ Wr0,
                                               const float* __restrict__ Wl1,
                                               const float* __restrict__ Wr1,
                                               u16* __restrict__ Wc0,
                                               u16* __restrict__ Wc1,
                                               const int* __restrict__ dst,
                                               int* __restrict__ deg,
                                               u16* __restrict__ H1,
                                               float* __restrict__ hl2) {
    int b = blockIdx.x;
    int tid = threadIdx.x;
    if (b < NB_CAST) {
        int i = b * 256 + tid;               // float4 index, exact
        float4 v = reinterpret_cast<const float4*>(x)[i];
        ushort4 o;
        o.x = f2bf(v.x); o.y = f2bf(v.y); o.z = f2bf(v.z); o.w = f2bf(v.w);
        reinterpret_cast<ushort4*>(xb)[i] = o;
    } else if (b < NB_CAST + NB_PREPW) {
        int t = (b - NB_CAST) * 256 + tid;   // 0..16383, exact
        int j = t >> 7, k = t & 127;
        Wc0[j * 256 + k]       = f2bf(Wl0[t]);
        Wc0[j * 256 + 128 + k] = f2bf(Wr0[t]);
        Wc1[j * 256 + k]       = f2bf(Wl1[t]);
        Wc1[j * 256 + 128 + k] = f2bf(Wr1[t]);
    } else if (b < NB_CAST + NB_PREPW + NB_DEG) {
        int e = (b - NB_CAST - NB_PREPW) * 256 + tid;
        if (e < NE) atomicAdd(&deg[dst[e]], 1);
    } else {
        // zero rows at index NN (targets of padded edges)
        if (tid < DD) { xb[(size_t)NN * DD + tid] = 0; H1[(size_t)NN * DD + tid] = 0; }
        if (tid < 16) hl2[(size_t)NN * 16 + tid] = 0.f;
    }
}

// ---------------- CSR build (padded to multiples of 8) ----------------

__global__ __launch_bounds__(256) void k_scan1(const int* __restrict__ deg,
                                               int* __restrict__ bsum,
                                               int* __restrict__ hist) {
    __shared__ int sm[256];
    __shared__ int lh[32];
    int t = threadIdx.x;
    if (t < 32) lh[t] = 0;
    int idx = blockIdx.x * 1024 + t * 4;
    int4 v = make_int4(0, 0, 0, 0);
    if (idx + 3 < NN) v = *reinterpret_cast<const int4*>(deg + idx);
    else {
        if (idx     < NN) v.x = deg[idx];
        if (idx + 1 < NN) v.y = deg[idx + 1];
        if (idx + 2 < NN) v.z = deg[idx + 2];
        if (idx + 3 < NN) v.w = deg[idx + 3];
    }
    int p0 = (v.x + 7) & ~7, p1 = (v.y + 7) & ~7, p2 = (v.z + 7) & ~7, p3 = (v.w + 7) & ~7;
    sm[t] = p0 + p1 + p2 + p3;
    __syncthreads();
    // histogram of iteration counts (pdeg/8), clamped to 31
    if (idx     < NN) atomicAdd(&lh[min(p0 >> 3, 31)], 1);
    if (idx + 1 < NN) atomicAdd(&lh[min(p1 >> 3, 31)], 1);
    if (idx + 2 < NN) atomicAdd(&lh[min(p2 >> 3, 31)], 1);
    if (idx + 3 < NN) atomicAdd(&lh[min(p3 >> 3, 31)], 1);
    __syncthreads();
    if (t < 32) atomicAdd(&hist[t], lh[t]);
    for (int off = 128; off > 0; off >>= 1) {
        if (t < off) sm[t] += sm[t + off];
        __syncthreads();
    }
    if (t == 0) bsum[blockIdx.x] = sm[0];
}

__global__ __launch_bounds__(128) void k_scan2(int* __restrict__ bsum,
                                               const int* __restrict__ hist,
                                               int* __restrict__ cursor) {
    __shared__ int sm[128];
    int t = threadIdx.x;
    int v = (t < NB_SCAN) ? bsum[t] : 0;
    sm[t] = v;
    __syncthreads();
    for (int off = 1; off < 128; off <<= 1) {
        int add = (t >= off) ? sm[t - off] : 0;
        __syncthreads();
        sm[t] += add;
        __syncthreads();
    }
    if (t < NB_SCAN) bsum[t] = (t == 0) ? 0 : sm[t - 1];  // exclusive, in-place
    if (t == 0) {   // exclusive scan of degree-bucket histogram
        int r = 0;
        for (int c = 0; c < 32; ++c) { int h = hist[c]; cursor[c] = r; r += h; }
    }
}

__global__ __launch_bounds__(256) void k_scan3(const int* __restrict__ deg,
                                               const int* __restrict__ boff,
                                               int* __restrict__ rp2,
                                               int* __restrict__ cur,
                                               float* __restrict__ inv,
                                               int* __restrict__ col2) {
    __shared__ int sm[256];
    int t = threadIdx.x;
    int idx = blockIdx.x * 1024 + t * 4;
    int4 v = make_int4(0, 0, 0, 0);
    if (idx + 3 < NN) v = *reinterpret_cast<const int4*>(deg + idx);
    else {
        if (idx     < NN) v.x = deg[idx];
        if (idx + 1 < NN) v.y = deg[idx + 1];
        if (idx + 2 < NN) v.z = deg[idx + 2];
        if (idx + 3 < NN) v.w = deg[idx + 3];
    }
    int p0 = (v.x + 7) & ~7, p1 = (v.y + 7) & ~7, p2 = (v.z + 7) & ~7, p3 = (v.w + 7) & ~7;
    sm[t] = p0 + p1 + p2 + p3;
    __syncthreads();
    for (int off = 1; off < 256; off <<= 1) {
        int add = (t >= off) ? sm[t - off] : 0;
        __syncthreads();
        sm[t] += add;
        __syncthreads();
    }
    int run = boff[blockIdx.x] + ((t == 0) ? 0 : sm[t - 1]);
    int d[4] = {v.x, v.y, v.z, v.w};
    int p[4] = {p0, p1, p2, p3};
#pragma unroll
    for (int i = 0; i < 4; ++i) {
        if (idx + i < NN) {
            rp2[idx + i] = run;
            cur[idx + i] = run;
            inv[idx + i] = 1.0f / (float)(d[i] > 0 ? d[i] : 1);
            for (int q = run + d[i]; q < run + p[i]; ++q) col2[q] = NN;  // pads -> zero row
            run += p[i];
        }
    }
    if (idx + 4 == NN) rp2[NN] = run;   // total padded edges (NN % 4 == 0)
}

// counting-sort nodes by iteration count -> perm (wave-uniform gather loops)
__global__ __launch_bounds__(256) void k_binscat(const int* __restrict__ deg,
                                                 int* __restrict__ cursor,
                                                 int* __restrict__ perm) {
    __shared__ int lcnt[32];
    __shared__ int lbase[32];
    int t = threadIdx.x;
    if (t < 32) lcnt[t] = 0;
    __syncthreads();
    int n = blockIdx.x * 256 + t;
    int c = 0, my = 0;
    if (n < NN) {
        c = min((deg[n] + 7) >> 3, 31);
        my = atomicAdd(&lcnt[c], 1);
    }
    __syncthreads();
    if (t < 32 && lcnt[t] > 0) lbase[t] = atomicAdd(&cursor[t], lcnt[t]);
    __syncthreads();
    if (n < NN) perm[lbase[c] + my] = n;
}

__global__ __launch_bounds__(256) void k_scatter(const int* __restrict__ src,
                                                 const int* __restrict__ dst,
                                                 int* __restrict__ cur,
                                                 int* __restrict__ col2) {
    int e = blockIdx.x * 256 + threadIdx.x;
    if (e < NE) {
        int p = atomicAdd(&cur[dst[e]], 1);
        col2[p] = src[e];
    }
}

// ---------------- fused SAGE layer (layers 0/1) ----------------
// One block = 16 nodes (via perm, degree-bucketed). Phase 1: mean-gather
// (8-deep fixed pipeline, padded lists) -> LDS [agg|x] K=256 swizzled.
// Phase 2: per-wave 16 nodes x 32 cols, W-frags from global (L2-hot), MFMA.

__global__ __launch_bounds__(256) void k_fused_layer(const u16* __restrict__ X,
                                                     const int* __restrict__ rp2,
                                                     const int* __restrict__ col2,
                                                     const float* __restrict__ inv,
                                                     const int* __restrict__ perm,
                                                     const u16* __restrict__ Wc,
                                                     const float* __restrict__ b,
                                                     u16* __restrict__ out) {
    __shared__ u16 XK[16 * 256];  // 8 KB; row = local node (512 B), swizzle: byte ^ (nl&7)<<4
    char* lds = reinterpret_cast<char*>(XK);

    int tid = threadIdx.x;
    int nl = tid >> 4;     // local node 0..15
    int sl = tid & 15;     // 16B k-slice 0..15
    int n = perm[blockIdx.x * 16 + nl];

    // self row -> LDS (K = 128 + sl*8)
    uint4 xv = *reinterpret_cast<const uint4*>(X + (size_t)n * DD + sl * 8);
    *reinterpret_cast<uint4*>(lds + nl * 512 + ((256 + sl * 16) ^ ((nl & 7) << 4))) = xv;

    // mean-gather: padded list, fixed 8-deep load pipeline
    int beg = rp2[n], end = rp2[n + 1];
    float a0 = 0.f, a1 = 0.f, a2 = 0.f, a3 = 0.f, a4 = 0.f, a5 = 0.f, a6 = 0.f, a7 = 0.f;
    for (int e = beg; e < end; e += 8) {
        int4 c0 = *reinterpret_cast<const int4*>(col2 + e);
        int4 c1 = *reinterpret_cast<const int4*>(col2 + e + 4);
        uint4 v0 = *reinterpret_cast<const uint4*>(X + (size_t)c0.x * DD + sl * 8);
        uint4 v1 = *reinterpret_cast<const uint4*>(X + (size_t)c0.y * DD + sl * 8);
        uint4 v2 = *reinterpret_cast<const uint4*>(X + (size_t)c0.z * DD + sl * 8);
        uint4 v3 = *reinterpret_cast<const uint4*>(X + (size_t)c0.w * DD + sl * 8);
        uint4 v4 = *reinterpret_cast<const uint4*>(X + (size_t)c1.x * DD + sl * 8);
        uint4 v5 = *reinterpret_cast<const uint4*>(X + (size_t)c1.y * DD + sl * 8);
        uint4 v6 = *reinterpret_cast<const uint4*>(X + (size_t)c1.z * DD + sl * 8);
        uint4 v7 = *reinterpret_cast<const uint4*>(X + (size_t)c1.w * DD + sl * 8);
        a0 += ((bflo(v0.x) + bflo(v1.x)) + (bflo(v2.x) + bflo(v3.x)))
            + ((bflo(v4.x) + bflo(v5.x)) + (bflo(v6.x) + bflo(v7.x)));
        a1 += ((bfhi(v0.x) + bfhi(v1.x)) + (bfhi(v2.x) + bfhi(v3.x)))
            + ((bfhi(v4.x) + bfhi(v5.x)) + (bfhi(v6.x) + bfhi(v7.x)));
        a2 += ((bflo(v0.y) + bflo(v1.y)) + (bflo(v2.y) + bflo(v3.y)))
            + ((bflo(v4.y) + bflo(v5.y)) + (bflo(v6.y) + bflo(v7.y)));
        a3 += ((bfhi(v0.y) + bfhi(v1.y)) + (bfhi(v2.y) + bfhi(v3.y)))
            + ((bfhi(v4.y) + bfhi(v5.y)) + (bfhi(v6.y) + bfhi(v7.y)));
        a4 += ((bflo(v0.z) + bflo(v1.z)) + (bflo(v2.z) + bflo(v3.z)))
            + ((bflo(v4.z) + bflo(v5.z)) + (bflo(v6.z) + bflo(v7.z)));
        a5 += ((bfhi(v0.z) + bfhi(v1.z)) + (bfhi(v2.z) + bfhi(v3.z)))
            + ((bfhi(v4.z) + bfhi(v5.z)) + (bfhi(v6.z) + bfhi(v7.z)));
        a6 += ((bflo(v0.w) + bflo(v1.w)) + (bflo(v2.w) + bflo(v3.w)))
            + ((bflo(v4.w) + bflo(v5.w)) + (bflo(v6.w) + bflo(v7.w)));
        a7 += ((bfhi(v0.w) + bfhi(v1.w)) + (bfhi(v2.w) + bfhi(v3.w)))
            + ((bfhi(v4.w) + bfhi(v5.w)) + (bfhi(v6.w) + bfhi(v7.w)));
    }
    float iv = inv[n];
    uint4 o;
    o.x = (u32)f2bf(a0 * iv) | ((u32)f2bf(a1 * iv) << 16);
    o.y = (u32)f2bf(a2 * iv) | ((u32)f2bf(a3 * iv) << 16);
    o.z = (u32)f2bf(a4 * iv) | ((u32)f2bf(a5 * iv) << 16);
    o.w = (u32)f2bf(a6 * iv) | ((u32)f2bf(a7 * iv) << 16);
    *reinterpret_cast<uint4*>(lds + nl * 512 + ((sl * 16) ^ ((nl & 7) << 4))) = o;
    __syncthreads();

    // ---- phase 2: GEMM ----
    int wid = tid >> 6, lane = tid & 63;
    int cl = lane & 15, rq = lane >> 4;

    f32x4 acc0 = (f32x4){0.f, 0.f, 0.f, 0.f};
    f32x4 acc1 = (f32x4){0.f, 0.f, 0.f, 0.f};
    const u16* wbase = Wc + (size_t)(wid * 32 + cl) * 256 + rq * 8;
    const char* xbase = lds + cl * 512;
    int xmask = (cl & 7) << 4;
#pragma unroll
    for (int ks = 0; ks < 8; ++ks) {
        bf16x8 xf = *reinterpret_cast<const bf16x8*>(xbase + ((ks * 64 + rq * 16) ^ xmask));
        bf16x8 w0 = *reinterpret_cast<const bf16x8*>(wbase + ks * 32);
        bf16x8 w1 = *reinterpret_cast<const bf16x8*>(wbase + 16 * 256 + ks * 32);
        acc0 = __builtin_amdgcn_mfma_f32_16x16x32_bf16(w0, xf, acc0, 0, 0, 0);
        acc1 = __builtin_amdgcn_mfma_f32_16x16x32_bf16(w1, xf, acc1, 0, 0, 0);
    }

    // epilogue: lane holds node perm[blk*16+cl], cols j = wid*32 + jf*16 + rq*4 + v
    int nout = perm[blockIdx.x * 16 + cl];
    u16* orow = out + (size_t)nout * DD + wid * 32 + rq * 4;
#pragma unroll
    for (int jf = 0; jf < 2; ++jf) {
        f32x4 a = jf ? acc1 : acc0;
        float4 bias = *reinterpret_cast<const float4*>(b + wid * 32 + jf * 16 + rq * 4);
        float o0 = fmaxf(a[0] + bias.x, 0.f);
        float o1 = fmaxf(a[1] + bias.y, 0.f);
        float o2 = fmaxf(a[2] + bias.z, 0.f);
        float o3 = fmaxf(a[3] + bias.w, 0.f);
        uint2 pk;
        pk.x = (u32)f2bf(o0) | ((u32)f2bf(o1) << 16);
        pk.y = (u32)f2bf(o2) | ((u32)f2bf(o3) << 16);
        *reinterpret_cast<uint2*>(orow + jf * 16) = pk;
    }
}

// ---------------- layer 2 ----------------

// hl2[n][j] = sum_k H[n][k] * Wl2[j][k]   (H bf16, W fp32 in LDS)
__global__ __launch_bounds__(256) void k_hl2(const u16* __restrict__ H,
                                             const float* __restrict__ Wl2,
                                             float* __restrict__ hl2) {
    __shared__ float Ws[16][128];
    int tid = threadIdx.x;
    for (int i = tid; i < 16 * 128; i += 256) Ws[i >> 7][i & 127] = Wl2[i];
    __syncthreads();
    int n = blockIdx.x * 256 + tid;
    if (n >= NN) return;
    const uint4* h4 = reinterpret_cast<const uint4*>(H + (size_t)n * DD);
    float acc[16];
#pragma unroll
    for (int j = 0; j < 16; ++j) acc[j] = 0.f;
    for (int c = 0; c < 16; ++c) {             // 8 bf16 per chunk
        uint4 hv = h4[c];
        float hf[8] = {bflo(hv.x), bfhi(hv.x), bflo(hv.y), bfhi(hv.y),
                       bflo(hv.z), bfhi(hv.z), bflo(hv.w), bfhi(hv.w)};
#pragma unroll
        for (int j = 0; j < 16; ++j) {
            const float4* w4 = reinterpret_cast<const float4*>(&Ws[j][c * 8]);
            float4 w0 = w4[0], w1 = w4[1];
            acc[j] += hf[0] * w0.x + hf[1] * w0.y + hf[2] * w0.z + hf[3] * w0.w
                    + hf[4] * w1.x + hf[5] * w1.y + hf[6] * w1.z + hf[7] * w1.w;
        }
    }
    float* dst = hl2 + (size_t)n * 16;
#pragma unroll
    for (int j4 = 0; j4 < 4; ++j4)
        *reinterpret_cast<float4*>(dst + j4 * 4) =
            make_float4(acc[j4 * 4], acc[j4 * 4 + 1], acc[j4 * 4 + 2], acc[j4 * 4 + 3]);
}

// fused: agg2 = mean-gather(hl2, padded); out = log_softmax(agg2 + H@Wr2^T + b2)
__global__ __launch_bounds__(256) void k_l2_fused(const u16* __restrict__ H,
                                                  const float* __restrict__ hl2,
                                                  const int* __restrict__ rp2,
                                                  const int* __restrict__ col2,
                                                  const float* __restrict__ inv,
                                                  const int* __restrict__ perm,
                                                  const float* __restrict__ Wr2,
                                                  const float* __restrict__ b2,
                                                  float* __restrict__ out) {
    __shared__ float Ws[16][128];
    __shared__ float bs[16];
    int tid = threadIdx.x;
    for (int i = tid; i < 16 * 128; i += 256) Ws[i >> 7][i & 127] = Wr2[i];
    if (tid < 16) bs[tid] = b2[tid];
    __syncthreads();
    int gid = blockIdx.x * 256 + tid;
    if (gid >= NN) return;
    int n = perm[gid];   // degree-bucketed -> wave-uniform loop counts

    // mean-gather of transformed neighbor features (16 floats/edge, 2-edge unroll)
    float ag[16];
#pragma unroll
    for (int j = 0; j < 16; ++j) ag[j] = 0.f;
    int beg = rp2[n], end = rp2[n + 1];
    for (int e = beg; e < end; e += 2) {
        const float4* r0 = reinterpret_cast<const float4*>(hl2 + (size_t)col2[e] * 16);
        const float4* r1 = reinterpret_cast<const float4*>(hl2 + (size_t)col2[e + 1] * 16);
        float4 p0 = r0[0], p1 = r0[1], p2 = r0[2], p3 = r0[3];
        float4 q0 = r1[0], q1 = r1[1], q2 = r1[2], q3 = r1[3];
        ag[0]  += p0.x + q0.x; ag[1]  += p0.y + q0.y; ag[2]  += p0.z + q0.z; ag[3]  += p0.w + q0.w;
        ag[4]  += p1.x + q1.x; ag[5]  += p1.y + q1.y; ag[6]  += p1.z + q1.z; ag[7]  += p1.w + q1.w;
        ag[8]  += p2.x + q2.x; ag[9]  += p2.y + q2.y; ag[10] += p2.z + q2.z; ag[11] += p2.w + q2.w;
        ag[12] += p3.x + q3.x; ag[13] += p3.y + q3.y; ag[14] += p3.z + q3.z; ag[15] += p3.w + q3.w;
    }
    float iv = inv[n];

    // self transform: H[n] @ Wr2^T
    const uint4* h4 = reinterpret_cast<const uint4*>(H + (size_t)n * DD);
    float acc[16];
#pragma unroll
    for (int j = 0; j < 16; ++j) acc[j] = 0.f;
    for (int c = 0; c < 16; ++c) {
        uint4 hv = h4[c];
        float hf[8] = {bflo(hv.x), bfhi(hv.x), bflo(hv.y), bfhi(hv.y),
                       bflo(hv.z), bfhi(hv.z), bflo(hv.w), bfhi(hv.w)};
#pragma unroll
        for (int j = 0; j < 16; ++j) {
            const float4* w4 = reinterpret_cast<const float4*>(&Ws[j][c * 8]);
            float4 w0 = w4[0], w1 = w4[1];
            acc[j] += hf[0] * w0.x + hf[1] * w0.y + hf[2] * w0.z + hf[3] * w0.w
                    + hf[4] * w1.x + hf[5] * w1.y + hf[6] * w1.z + hf[7] * w1.w;
        }
    }

    float v[16];
    float m = -1e30f;
#pragma unroll
    for (int j = 0; j < 16; ++j) {
        v[j] = acc[j] + bs[j] + ag[j] * iv;
        m = fmaxf(m, v[j]);
    }
    float s = 0.f;
#pragma unroll
    for (int j = 0; j < 16; ++j) s += expf(v[j] - m);
    float lse = m + logf(s);
    float* dst = out + (size_t)n * 16;
#pragma unroll
    for (int j4 = 0; j4 < 4; ++j4)
        *reinterpret_cast<float4*>(dst + j4 * 4) =
            make_float4(v[j4 * 4] - lse, v[j4 * 4 + 1] - lse, v[j4 * 4 + 2] - lse, v[j4 * 4 + 3] - lse);
}

// ---------------- host launcher ----------------

extern "C" void kernel_launch(void* const* d_in, const int* in_sizes, int n_in,
                              void* d_out, int out_size, void* d_ws, size_t ws_size,
                              hipStream_t stream) {
    const float* x   = (const float*)d_in[0];
    const int*   ei  = (const int*)d_in[1];
    const float* Wl0 = (const float*)d_in[2];
    const float* bl0 = (const float*)d_in[3];
    const float* Wr0 = (const float*)d_in[4];
    const float* Wl1 = (const float*)d_in[5];
    const float* bl1 = (const float*)d_in[6];
    const float* Wr1 = (const float*)d_in[7];
    const float* Wl2 = (const float*)d_in[8];
    const float* bl2 = (const float*)d_in[9];
    const float* Wr2 = (const float*)d_in[10];
    float* out = (float*)d_out;

    const int* e_src = ei;       // edge_index[0]
    const int* e_dst = ei + NE;  // edge_index[1]

    // workspace carve-out (256B aligned)
    char* ws = (char*)d_ws;
    size_t off = 0;
    auto carve = [&](size_t bytes) -> void* {
        void* p = ws + off;
        off = (off + bytes + 255) & ~(size_t)255;
        return p;
    };
    int*   deg  = (int*)carve((size_t)(NN + 128) * 4);  // deg | hist(32) | cursor(32)
    int*   hist = deg + NN;
    int*   curs = deg + NN + 32;
    int*   rp2  = (int*)carve((size_t)(NN + 1) * 4);
    int*   cur  = (int*)carve((size_t)NN * 4);
    int*   bsum = (int*)carve(512 * 4);
    int*   col2 = (int*)carve((size_t)(NE + 7 * NN + 64) * 4);  // padded CSR
    int*   perm = (int*)carve((size_t)NN * 4);
    float* inv  = (float*)carve((size_t)NN * 4);
    u16*   xb   = (u16*)carve((size_t)(NN + 1) * DD * 2);       // +1: zero row
    u16*   H1   = (u16*)carve((size_t)(NN + 1) * DD * 2);       // +1: zero row
    u16*   H2   = (u16*)carve((size_t)NN * DD * 2);
    u16*   Wc0  = (u16*)carve((size_t)128 * 256 * 2);
    u16*   Wc1  = (u16*)carve((size_t)128 * 256 * 2);
    float* hl2  = (float*)carve((size_t)(NN + 1) * 16 * 4);     // +1: zero row
    (void)ws_size; (void)in_sizes; (void)n_in; (void)out_size;

    // setup: zero {deg|hist|cursor}, then {cast | weight-prep | degree | zero-rows}
    hipMemsetAsync(deg, 0, (size_t)(NN + 128) * 4, stream);
    k_setup<<<NB_CAST + NB_PREPW + NB_DEG + 1, 256, 0, stream>>>(
        x, xb, Wl0, Wr0, Wl1, Wr1, Wc0, Wc1, e_dst, deg, H1, hl2);

    // padded CSR build + degree-bucket permutation
    k_scan1<<<NB_SCAN, 256, 0, stream>>>(deg, bsum, hist);
    k_scan2<<<1, 128, 0, stream>>>(bsum, hist, curs);
    k_scan3<<<NB_SCAN, 256, 0, stream>>>(deg, bsum, rp2, cur, inv, col2);
    k_binscat<<<(NN + 255) / 256, 256, 0, stream>>>(deg, curs, perm);
    k_scatter<<<(NE + 255) / 256, 256, 0, stream>>>(e_src, e_dst, cur, col2);

    // layer 0: H1 = relu([mean-gather(xb) | xb] @ Wc0 + bl0)   (fused)
    k_fused_layer<<<NN / 16, 256, 0, stream>>>(xb, rp2, col2, inv, perm, Wc0, bl0, H1);

    // layer 1: H2 = relu([mean-gather(H1) | H1] @ Wc1 + bl1)   (fused)
    k_fused_layer<<<NN / 16, 256, 0, stream>>>(H1, rp2, col2, inv, perm, Wc1, bl1, H2);

    // layer 2: transform-first, then fused {16-wide gather + log_softmax}
    k_hl2<<<(NN + 255) / 256, 256, 0, stream>>>(H2, Wl2, hl2);
    k_l2_fused<<<(NN + 255) / 256, 256, 0, stream>>>(H2, hl2, rp2, col2, inv, perm, Wr2, bl2, out);
}

// Round 8
// 240.434 us; speedup vs baseline: 1.2085x; 1.1541x over previous
//
#include <hip/hip_runtime.h>
#include <math.h>

#define NN 100000   // nodes
#define NE 600000   // edges
#define DD 128      // hidden dim
#define NB_SCAN 98  // ceil(NN/1024)

// k_setup grid sections
#define NB_CAST 12500   // NN*32 float4s / 256
#define NB_PREPW 64     // 128*128 / 256
#define NB_PREPW2 8     // 16*128 / 256
#define NB_DEG 2344     // ceil(NE/256)

typedef __attribute__((ext_vector_type(8))) short bf16x8;
typedef __attribute__((ext_vector_type(4))) float f32x4;
typedef unsigned short u16;
typedef unsigned int u32;

__device__ __forceinline__ float bflo(u32 w) {
    union { u32 i; float f; } v; v.i = w << 16; return v.f;
}
__device__ __forceinline__ float bfhi(u32 w) {
    union { u32 i; float f; } v; v.i = w & 0xffff0000u; return v.f;
}
__device__ __forceinline__ u16 f2bf(float f) {
    union { float f; u32 u; } v; v.f = f;
    u32 r = v.u + 0x7fffu + ((v.u >> 16) & 1u);  // RNE
    return (u16)(r >> 16);
}

// ---------------- setup: cast + weight prep + degree + zero-rows ----------

__global__ __launch_bounds__(256) void k_setup(const float* __restrict__ x,
                                               u16* __restrict__ xb,
                                               const float* __restrict__ Wl0,
                                               const float* __restrict__ Wr0,
                                               const float* __restrict__ Wl1,
                                               const float* __restrict__ Wr1,
                                               const float* __restrict__ Wl2,
                                               const float* __restrict__ Wr2,
                                               u16* __restrict__ Wc0,
                                               u16* __restrict__ Wc1,
                                               u16* __restrict__ Wc2,
                                               const int* __restrict__ dst,
                                               int* __restrict__ deg,
                                               u16* __restrict__ H1,
                                               u16* __restrict__ hl2b) {
    int b = blockIdx.x;
    int tid = threadIdx.x;
    if (b < NB_CAST) {
        int i = b * 256 + tid;               // float4 index, exact
        float4 v = reinterpret_cast<const float4*>(x)[i];
        ushort4 o;
        o.x = f2bf(v.x); o.y = f2bf(v.y); o.z = f2bf(v.z); o.w = f2bf(v.w);
        reinterpret_cast<ushort4*>(xb)[i] = o;
    } else if (b < NB_CAST + NB_PREPW) {
        int t = (b - NB_CAST) * 256 + tid;   // 0..16383, exact
        int j = t >> 7, k = t & 127;
        Wc0[j * 256 + k]       = f2bf(Wl0[t]);
        Wc0[j * 256 + 128 + k] = f2bf(Wr0[t]);
        Wc1[j * 256 + k]       = f2bf(Wl1[t]);
        Wc1[j * 256 + 128 + k] = f2bf(Wr1[t]);
    } else if (b < NB_CAST + NB_PREPW + NB_PREPW2) {
        int t = (b - NB_CAST - NB_PREPW) * 256 + tid;  // 0..2047
        int j = t >> 7, k = t & 127;
        Wc2[j * 128 + k]        = f2bf(Wl2[t]);
        Wc2[(16 + j) * 128 + k] = f2bf(Wr2[t]);
    } else if (b < NB_CAST + NB_PREPW + NB_PREPW2 + NB_DEG) {
        int e = (b - NB_CAST - NB_PREPW - NB_PREPW2) * 256 + tid;
        if (e < NE) atomicAdd(&deg[dst[e]], 1);
    } else {
        // zero rows at index NN (targets of padded edges)
        if (tid < DD) { xb[(size_t)NN * DD + tid] = 0; H1[(size_t)NN * DD + tid] = 0; }
        if (tid < 16) hl2b[(size_t)NN * 16 + tid] = 0;
    }
}

// ---------------- CSR build (padded to multiples of 8) ----------------

__global__ __launch_bounds__(256) void k_scan1(const int* __restrict__ deg,
                                               int* __restrict__ bsum,
                                               int* __restrict__ hist) {
    __shared__ int sm[256];
    __shared__ int lh[32];
    int t = threadIdx.x;
    if (t < 32) lh[t] = 0;
    int idx = blockIdx.x * 1024 + t * 4;
    int4 v = make_int4(0, 0, 0, 0);
    if (idx + 3 < NN) v = *reinterpret_cast<const int4*>(deg + idx);
    else {
        if (idx     < NN) v.x = deg[idx];
        if (idx + 1 < NN) v.y = deg[idx + 1];
        if (idx + 2 < NN) v.z = deg[idx + 2];
        if (idx + 3 < NN) v.w = deg[idx + 3];
    }
    int p0 = (v.x + 7) & ~7, p1 = (v.y + 7) & ~7, p2 = (v.z + 7) & ~7, p3 = (v.w + 7) & ~7;
    sm[t] = p0 + p1 + p2 + p3;
    __syncthreads();
    if (idx     < NN) atomicAdd(&lh[min(p0 >> 3, 31)], 1);
    if (idx + 1 < NN) atomicAdd(&lh[min(p1 >> 3, 31)], 1);
    if (idx + 2 < NN) atomicAdd(&lh[min(p2 >> 3, 31)], 1);
    if (idx + 3 < NN) atomicAdd(&lh[min(p3 >> 3, 31)], 1);
    __syncthreads();
    if (t < 32) atomicAdd(&hist[t], lh[t]);
    for (int off = 128; off > 0; off >>= 1) {
        if (t < off) sm[t] += sm[t + off];
        __syncthreads();
    }
    if (t == 0) bsum[blockIdx.x] = sm[0];
}

__global__ __launch_bounds__(128) void k_scan2(int* __restrict__ bsum,
                                               const int* __restrict__ hist,
                                               int* __restrict__ cursor) {
    __shared__ int sm[128];
    int t = threadIdx.x;
    int v = (t < NB_SCAN) ? bsum[t] : 0;
    sm[t] = v;
    __syncthreads();
    for (int off = 1; off < 128; off <<= 1) {
        int add = (t >= off) ? sm[t - off] : 0;
        __syncthreads();
        sm[t] += add;
        __syncthreads();
    }
    if (t < NB_SCAN) bsum[t] = (t == 0) ? 0 : sm[t - 1];  // exclusive, in-place
    if (t == 0) {   // DESCENDING bucket order: heavy blocks dispatched first
        int r = 0;
        for (int c = 31; c >= 0; --c) { cursor[c] = r; r += hist[c]; }
    }
}

// scan3: padded CSR offsets + pad-fill + per-node descriptor (bucketed order)
__global__ __launch_bounds__(256) void k_scan3(const int* __restrict__ deg,
                                               const int* __restrict__ boff,
                                               int* __restrict__ cur,
                                               int* __restrict__ col2,
                                               int* __restrict__ cursor,
                                               int4* __restrict__ desc) {
    __shared__ int sm[256];
    __shared__ int lh[32];
    __shared__ int lb[32];
    int t = threadIdx.x;
    if (t < 32) lh[t] = 0;
    int idx = blockIdx.x * 1024 + t * 4;
    int4 v = make_int4(0, 0, 0, 0);
    if (idx + 3 < NN) v = *reinterpret_cast<const int4*>(deg + idx);
    else {
        if (idx     < NN) v.x = deg[idx];
        if (idx + 1 < NN) v.y = deg[idx + 1];
        if (idx + 2 < NN) v.z = deg[idx + 2];
        if (idx + 3 < NN) v.w = deg[idx + 3];
    }
    int p0 = (v.x + 7) & ~7, p1 = (v.y + 7) & ~7, p2 = (v.z + 7) & ~7, p3 = (v.w + 7) & ~7;
    sm[t] = p0 + p1 + p2 + p3;
    __syncthreads();
    for (int off = 1; off < 256; off <<= 1) {
        int add = (t >= off) ? sm[t - off] : 0;
        __syncthreads();
        sm[t] += add;
        __syncthreads();
    }
    int run = boff[blockIdx.x] + ((t == 0) ? 0 : sm[t - 1]);
    int d[4] = {v.x, v.y, v.z, v.w};
    int p[4] = {p0, p1, p2, p3};
    int begs[4], ci[4], myi[4];
#pragma unroll
    for (int i = 0; i < 4; ++i) {
        if (idx + i < NN) {
            begs[i] = run;
            cur[idx + i] = run;
            for (int q = run + d[i]; q < run + p[i]; ++q) col2[q] = NN;  // pads -> zero row
            ci[i] = min(p[i] >> 3, 31);
            myi[i] = atomicAdd(&lh[ci[i]], 1);
            run += p[i];
        }
    }
    __syncthreads();
    if (t < 32 && lh[t] > 0) lb[t] = atomicAdd(&cursor[t], lh[t]);
    __syncthreads();
#pragma unroll
    for (int i = 0; i < 4; ++i) {
        if (idx + i < NN) {
            float iv = 1.0f / (float)(d[i] > 0 ? d[i] : 1);
            desc[lb[ci[i]] + myi[i]] =
                make_int4(idx + i, begs[i], begs[i] + p[i], __float_as_int(iv));
        }
    }
}

__global__ __launch_bounds__(256) void k_scatter(const int* __restrict__ src,
                                                 const int* __restrict__ dst,
                                                 int* __restrict__ cur,
                                                 int* __restrict__ col2) {
    int e = blockIdx.x * 256 + threadIdx.x;
    if (e < NE) {
        int p = atomicAdd(&cur[dst[e]], 1);
        col2[p] = src[e];
    }
}

// ---------------- fused SAGE layer (layers 0/1) ----------------
// One block = 16 nodes via desc (degree-bucketed, heavy-first). Phase 1:
// mean-gather (8-deep fixed pipeline, padded lists) -> LDS [agg|x] K=256
// swizzled. Phase 2: per-wave 16 nodes x 32 cols, W-frags from global
// (L2-hot), MFMA. Epilogue: transpose through LDS -> full 256B-row stores.

__global__ __launch_bounds__(256) void k_fused_layer(const u16* __restrict__ X,
                                                     const int* __restrict__ col2,
                                                     const int4* __restrict__ desc,
                                                     const u16* __restrict__ Wc,
                                                     const float* __restrict__ b,
                                                     u16* __restrict__ out) {
    __shared__ u16 XK[16 * 256];  // 8 KB; row = local node (512 B), swizzle: byte ^ (r&7)<<4
    char* lds = reinterpret_cast<char*>(XK);

    int tid = threadIdx.x;
    int nl = tid >> 4;     // local node 0..15
    int sl = tid & 15;     // 16B k-slice 0..15
    int4 d = desc[blockIdx.x * 16 + nl];
    int n = d.x, beg = d.y, end = d.z;
    float iv = __int_as_float(d.w);

    // self row -> LDS (K = 128 + sl*8)
    uint4 xv = *reinterpret_cast<const uint4*>(X + (size_t)n * DD + sl * 8);
    *reinterpret_cast<uint4*>(lds + nl * 512 + ((256 + sl * 16) ^ ((nl & 7) << 4))) = xv;

    // mean-gather: padded list, fixed 8-deep load pipeline
    float a0 = 0.f, a1 = 0.f, a2 = 0.f, a3 = 0.f, a4 = 0.f, a5 = 0.f, a6 = 0.f, a7 = 0.f;
    for (int e = beg; e < end; e += 8) {
        int4 c0 = *reinterpret_cast<const int4*>(col2 + e);
        int4 c1 = *reinterpret_cast<const int4*>(col2 + e + 4);
        uint4 v0 = *reinterpret_cast<const uint4*>(X + (size_t)c0.x * DD + sl * 8);
        uint4 v1 = *reinterpret_cast<const uint4*>(X + (size_t)c0.y * DD + sl * 8);
        uint4 v2 = *reinterpret_cast<const uint4*>(X + (size_t)c0.z * DD + sl * 8);
        uint4 v3 = *reinterpret_cast<const uint4*>(X + (size_t)c0.w * DD + sl * 8);
        uint4 v4 = *reinterpret_cast<const uint4*>(X + (size_t)c1.x * DD + sl * 8);
        uint4 v5 = *reinterpret_cast<const uint4*>(X + (size_t)c1.y * DD + sl * 8);
        uint4 v6 = *reinterpret_cast<const uint4*>(X + (size_t)c1.z * DD + sl * 8);
        uint4 v7 = *reinterpret_cast<const uint4*>(X + (size_t)c1.w * DD + sl * 8);
        a0 += ((bflo(v0.x) + bflo(v1.x)) + (bflo(v2.x) + bflo(v3.x)))
            + ((bflo(v4.x) + bflo(v5.x)) + (bflo(v6.x) + bflo(v7.x)));
        a1 += ((bfhi(v0.x) + bfhi(v1.x)) + (bfhi(v2.x) + bfhi(v3.x)))
            + ((bfhi(v4.x) + bfhi(v5.x)) + (bfhi(v6.x) + bfhi(v7.x)));
        a2 += ((bflo(v0.y) + bflo(v1.y)) + (bflo(v2.y) + bflo(v3.y)))
            + ((bflo(v4.y) + bflo(v5.y)) + (bflo(v6.y) + bflo(v7.y)));
        a3 += ((bfhi(v0.y) + bfhi(v1.y)) + (bfhi(v2.y) + bfhi(v3.y)))
            + ((bfhi(v4.y) + bfhi(v5.y)) + (bfhi(v6.y) + bfhi(v7.y)));
        a4 += ((bflo(v0.z) + bflo(v1.z)) + (bflo(v2.z) + bflo(v3.z)))
            + ((bflo(v4.z) + bflo(v5.z)) + (bflo(v6.z) + bflo(v7.z)));
        a5 += ((bfhi(v0.z) + bfhi(v1.z)) + (bfhi(v2.z) + bfhi(v3.z)))
            + ((bfhi(v4.z) + bfhi(v5.z)) + (bfhi(v6.z) + bfhi(v7.z)));
        a6 += ((bflo(v0.w) + bflo(v1.w)) + (bflo(v2.w) + bflo(v3.w)))
            + ((bflo(v4.w) + bflo(v5.w)) + (bflo(v6.w) + bflo(v7.w)));
        a7 += ((bfhi(v0.w) + bfhi(v1.w)) + (bfhi(v2.w) + bfhi(v3.w)))
            + ((bfhi(v4.w) + bfhi(v5.w)) + (bfhi(v6.w) + bfhi(v7.w)));
    }
    uint4 o;
    o.x = (u32)f2bf(a0 * iv) | ((u32)f2bf(a1 * iv) << 16);
    o.y = (u32)f2bf(a2 * iv) | ((u32)f2bf(a3 * iv) << 16);
    o.z = (u32)f2bf(a4 * iv) | ((u32)f2bf(a5 * iv) << 16);
    o.w = (u32)f2bf(a6 * iv) | ((u32)f2bf(a7 * iv) << 16);
    *reinterpret_cast<uint4*>(lds + nl * 512 + ((sl * 16) ^ ((nl & 7) << 4))) = o;
    __syncthreads();

    // ---- phase 2: GEMM ----
    int wid = tid >> 6, lane = tid & 63;
    int cl = lane & 15, rq = lane >> 4;

    f32x4 acc0 = (f32x4){0.f, 0.f, 0.f, 0.f};
    f32x4 acc1 = (f32x4){0.f, 0.f, 0.f, 0.f};
    const u16* wbase = Wc + (size_t)(wid * 32 + cl) * 256 + rq * 8;
    const char* xbase = lds + cl * 512;
    int xmask = (cl & 7) << 4;
#pragma unroll
    for (int ks = 0; ks < 8; ++ks) {
        bf16x8 xf = *reinterpret_cast<const bf16x8*>(xbase + ((ks * 64 + rq * 16) ^ xmask));
        bf16x8 w0 = *reinterpret_cast<const bf16x8*>(wbase + ks * 32);
        bf16x8 w1 = *reinterpret_cast<const bf16x8*>(wbase + 16 * 256 + ks * 32);
        acc0 = __builtin_amdgcn_mfma_f32_16x16x32_bf16(w0, xf, acc0, 0, 0, 0);
        acc1 = __builtin_amdgcn_mfma_f32_16x16x32_bf16(w1, xf, acc1, 0, 0, 0);
    }
    __syncthreads();   // XK reads done; safe to overwrite with output tile

    // bias + relu + pack -> LDS (node-row cl, col bytes (j*2)^swz; 256B/row used)
#pragma unroll
    for (int jf = 0; jf < 2; ++jf) {
        f32x4 a = jf ? acc1 : acc0;
        int j0 = wid * 32 + jf * 16 + rq * 4;
        float4 bias = *reinterpret_cast<const float4*>(b + j0);
        float o0 = fmaxf(a[0] + bias.x, 0.f);
        float o1 = fmaxf(a[1] + bias.y, 0.f);
        float o2 = fmaxf(a[2] + bias.z, 0.f);
        float o3 = fmaxf(a[3] + bias.w, 0.f);
        uint2 pk;
        pk.x = (u32)f2bf(o0) | ((u32)f2bf(o1) << 16);
        pk.y = (u32)f2bf(o2) | ((u32)f2bf(o3) << 16);
        *reinterpret_cast<uint2*>(lds + cl * 512 + ((j0 * 2) ^ ((cl & 7) << 4))) = pk;
    }
    __syncthreads();

    // full-row stores: thread (nl, sl) stores bytes [sl*16, sl*16+16) of row n
    // (output row = 128 cols x 2B = 256B; 16 threads x 16B cover it exactly)
    uint4 ov = *reinterpret_cast<const uint4*>(lds + nl * 512 + ((sl * 16) ^ ((nl & 7) << 4)));
    *reinterpret_cast<uint4*>(out + (size_t)n * DD + sl * 8) = ov;
}

// ---------------- layer 2 ----------------

// k_l2t: hl2b = bf16(H@Wl2^T), hr2 = fp32(H@Wr2^T) via MFMA.
// Block = 32 nodes; wave w: node-half (w>>1), table (w&1).
__global__ __launch_bounds__(256) void k_l2t(const u16* __restrict__ H,
                                             const u16* __restrict__ Wc2,
                                             u16* __restrict__ hl2b,
                                             float* __restrict__ hr2) {
    __shared__ u16 HS[32 * 128];  // 8 KB, rows 256B, swizzle byte ^ (r&7)<<4
    char* lds = reinterpret_cast<char*>(HS);
    int tid = threadIdx.x;
    int r0 = tid >> 4, c0 = tid & 15;
#pragma unroll
    for (int p = 0; p < 2; ++p) {
        int r = p * 16 + r0;
        uint4 v = *reinterpret_cast<const uint4*>(H + (size_t)(blockIdx.x * 32 + r) * DD + c0 * 8);
        *reinterpret_cast<uint4*>(lds + r * 256 + ((c0 * 16) ^ ((r & 7) << 4))) = v;
    }
    __syncthreads();

    int wid = tid >> 6, lane = tid & 63, cl = lane & 15, rq = lane >> 4;
    int h = wid >> 1, jf = wid & 1;
    f32x4 acc = (f32x4){0.f, 0.f, 0.f, 0.f};
    const u16* wb = Wc2 + (size_t)(jf * 16 + cl) * 128 + rq * 8;
    int row = h * 16 + cl;
    const char* xb2 = lds + row * 256;
    int xm = (row & 7) << 4;
#pragma unroll
    for (int ks = 0; ks < 4; ++ks) {
        bf16x8 xf = *reinterpret_cast<const bf16x8*>(xb2 + ((ks * 64 + rq * 16) ^ xm));
        bf16x8 wf = *reinterpret_cast<const bf16x8*>(wb + ks * 32);
        acc = __builtin_amdgcn_mfma_f32_16x16x32_bf16(wf, xf, acc, 0, 0, 0);
    }
    int n = blockIdx.x * 32 + h * 16 + cl;
    if (jf == 0) {
        uint2 pk;
        pk.x = (u32)f2bf(acc[0]) | ((u32)f2bf(acc[1]) << 16);
        pk.y = (u32)f2bf(acc[2]) | ((u32)f2bf(acc[3]) << 16);
        *reinterpret_cast<uint2*>(hl2b + (size_t)n * 16 + rq * 4) = pk;
    } else {
        *reinterpret_cast<float4*>(hr2 + (size_t)n * 16 + rq * 4) =
            make_float4(acc[0], acc[1], acc[2], acc[3]);
    }
}

// k_l2_final: 8 lanes/node mean-gather(hl2b) + hr2 + bias -> log_softmax.
__global__ __launch_bounds__(256) void k_l2_final(const u16* __restrict__ hl2b,
                                                  const float* __restrict__ hr2,
                                                  const int* __restrict__ col2,
                                                  const int4* __restrict__ desc,
                                                  const float* __restrict__ b2,
                                                  float* __restrict__ out) {
    int tid = threadIdx.x;
    int ns = tid >> 3;   // node slot 0..31
    int l  = tid & 7;
    int4 d = desc[blockIdx.x * 32 + ns];
    int n = d.x, beg = d.y, end = d.z;
    float iv = __int_as_float(d.w);

    float ag[16];
#pragma unroll
    for (int j = 0; j < 16; ++j) ag[j] = 0.f;
    for (int e = beg + l; e < end; e += 8) {
        const u16* r = hl2b + (size_t)col2[e] * 16;
        uint4 h0 = *reinterpret_cast<const uint4*>(r);
        uint4 h1 = *reinterpret_cast<const uint4*>(r + 8);
        ag[0] += bflo(h0.x); ag[1] += bfhi(h0.x); ag[2]  += bflo(h0.y); ag[3]  += bfhi(h0.y);
        ag[4] += bflo(h0.z); ag[5] += bfhi(h0.z); ag[6]  += bflo(h0.w); ag[7]  += bfhi(h0.w);
        ag[8] += bflo(h1.x); ag[9] += bfhi(h1.x); ag[10] += bflo(h1.y); ag[11] += bfhi(h1.y);
        ag[12] += bflo(h1.z); ag[13] += bfhi(h1.z); ag[14] += bflo(h1.w); ag[15] += bfhi(h1.w);
    }
#pragma unroll
    for (int m = 1; m <= 4; m <<= 1) {
#pragma unroll
        for (int j = 0; j < 16; ++j) ag[j] += __shfl_xor(ag[j], m);
    }
    if (l < 4) {
        float4 hr = *reinterpret_cast<const float4*>(hr2 + (size_t)n * 16 + l * 4);
        float4 bb = *reinterpret_cast<const float4*>(b2 + l * 4);
        float v0 = hr.x + bb.x + ag[l * 4 + 0] * iv;
        float v1 = hr.y + bb.y + ag[l * 4 + 1] * iv;
        float v2 = hr.z + bb.z + ag[l * 4 + 2] * iv;
        float v3 = hr.w + bb.w + ag[l * 4 + 3] * iv;
        float m4 = fmaxf(fmaxf(v0, v1), fmaxf(v2, v3));
        m4 = fmaxf(m4, __shfl_xor(m4, 1));
        m4 = fmaxf(m4, __shfl_xor(m4, 2));
        float s4 = expf(v0 - m4) + expf(v1 - m4) + expf(v2 - m4) + expf(v3 - m4);
        s4 += __shfl_xor(s4, 1);
        s4 += __shfl_xor(s4, 2);
        float lse = m4 + logf(s4);
        *reinterpret_cast<float4*>(out + (size_t)n * 16 + l * 4) =
            make_float4(v0 - lse, v1 - lse, v2 - lse, v3 - lse);
    }
}

// ---------------- host launcher ----------------

extern "C" void kernel_launch(void* const* d_in, const int* in_sizes, int n_in,
                              void* d_out, int out_size, void* d_ws, size_t ws_size,
                              hipStream_t stream) {
    const float* x   = (const float*)d_in[0];
    const int*   ei  = (const int*)d_in[1];
    const float* Wl0 = (const float*)d_in[2];
    const float* bl0 = (const float*)d_in[3];
    const float* Wr0 = (const float*)d_in[4];
    const float* Wl1 = (const float*)d_in[5];
    const float* bl1 = (const float*)d_in[6];
    const float* Wr1 = (const float*)d_in[7];
    const float* Wl2 = (const float*)d_in[8];
    const float* bl2 = (const float*)d_in[9];
    const float* Wr2 = (const float*)d_in[10];
    float* out = (float*)d_out;

    const int* e_src = ei;       // edge_index[0]
    const int* e_dst = ei + NE;  // edge_index[1]

    // workspace carve-out (256B aligned)
    char* ws = (char*)d_ws;
    size_t off = 0;
    auto carve = [&](size_t bytes) -> void* {
        void* p = ws + off;
        off = (off + bytes + 255) & ~(size_t)255;
        return p;
    };
    int*   deg  = (int*)carve((size_t)(NN + 128) * 4);  // deg | hist(32) | cursor(32)
    int*   hist = deg + NN;
    int*   curs = deg + NN + 32;
    int*   cur  = (int*)carve((size_t)NN * 4);
    int*   bsum = (int*)carve(512 * 4);
    int*   col2 = (int*)carve((size_t)(NE + 7 * NN + 64) * 4);  // padded CSR
    int4*  desc = (int4*)carve((size_t)NN * 16);
    u16*   xb   = (u16*)carve((size_t)(NN + 1) * DD * 2);       // +1: zero row
    u16*   H1   = (u16*)carve((size_t)(NN + 1) * DD * 2);       // +1: zero row
    u16*   H2   = (u16*)carve((size_t)NN * DD * 2);
    u16*   Wc0  = (u16*)carve((size_t)128 * 256 * 2);
    u16*   Wc1  = (u16*)carve((size_t)128 * 256 * 2);
    u16*   Wc2  = (u16*)carve((size_t)32 * 128 * 2);
    u16*   hl2b = (u16*)carve((size_t)(NN + 1) * 16 * 2);       // +1: zero row
    float* hr2  = (float*)carve((size_t)NN * 16 * 4);
    (void)ws_size; (void)in_sizes; (void)n_in; (void)out_size;

    // setup: zero {deg|hist|cursor}, then sectioned prep
    hipMemsetAsync(deg, 0, (size_t)(NN + 128) * 4, stream);
    k_setup<<<NB_CAST + NB_PREPW + NB_PREPW2 + NB_DEG + 1, 256, 0, stream>>>(
        x, xb, Wl0, Wr0, Wl1, Wr1, Wl2, Wr2, Wc0, Wc1, Wc2, e_dst, deg, H1, hl2b);

    // padded CSR + descriptor (degree-bucketed, heavy-first)
    k_scan1<<<NB_SCAN, 256, 0, stream>>>(deg, bsum, hist);
    k_scan2<<<1, 128, 0, stream>>>(bsum, hist, curs);
    k_scan3<<<NB_SCAN, 256, 0, stream>>>(deg, bsum, cur, col2, curs, desc);
    k_scatter<<<(NE + 255) / 256, 256, 0, stream>>>(e_src, e_dst, cur, col2);

    // layer 0 & 1 (fused gather + MFMA)
    k_fused_layer<<<NN / 16, 256, 0, stream>>>(xb, col2, desc, Wc0, bl0, H1);
    k_fused_layer<<<NN / 16, 256, 0, stream>>>(H1, col2, desc, Wc1, bl1, H2);

    // layer 2: dual transform (MFMA), then fused gather + log_softmax
    k_l2t<<<NN / 32, 256, 0, stream>>>(H2, Wc2, hl2b, hr2);
    k_l2_final<<<NN / 32, 256, 0, stream>>>(hl2b, hr2, col2, desc, bl2, out);
}

// Round 9
// 203.053 us; speedup vs baseline: 1.4309x; 1.1841x over previous
//
#include <hip/hip_runtime.h>
#include <math.h>

#define NN 100000   // nodes
#define NE 600000   // edges
#define DD 128      // hidden dim
#define NB_SCAN 98  // ceil(NN/1024)

// k_setup grid sections
#define NB_CAST 12500   // NN*32 float4s / 256
#define NB_PREPW 64     // 128*128 / 256
#define NB_PREPW2 8     // 16*128 / 256
#define NB_DEG 2344     // ceil(NE/256)

typedef __attribute__((ext_vector_type(8))) short bf16x8;
typedef __attribute__((ext_vector_type(4))) float f32x4;
typedef unsigned short u16;
typedef unsigned int u32;

__device__ __forceinline__ float bflo(u32 w) {
    union { u32 i; float f; } v; v.i = w << 16; return v.f;
}
__device__ __forceinline__ float bfhi(u32 w) {
    union { u32 i; float f; } v; v.i = w & 0xffff0000u; return v.f;
}
__device__ __forceinline__ u16 f2bf(float f) {
    union { float f; u32 u; } v; v.f = f;
    u32 r = v.u + 0x7fffu + ((v.u >> 16) & 1u);  // RNE
    return (u16)(r >> 16);
}

// ---------------- setup: cast + weight prep + degree + zero-rows ----------

__global__ __launch_bounds__(256) void k_setup(const float* __restrict__ x,
                                               u16* __restrict__ xb,
                                               const float* __restrict__ Wl0,
                                               const float* __restrict__ Wr0,
                                               const float* __restrict__ Wl1,
                                               const float* __restrict__ Wr1,
                                               const float* __restrict__ Wl2,
                                               const float* __restrict__ Wr2,
                                               u16* __restrict__ Wc0,
                                               u16* __restrict__ Wc1,
                                               u16* __restrict__ Wc2,
                                               const int* __restrict__ dst,
                                               int* __restrict__ deg,
                                               u16* __restrict__ H1,
                                               u16* __restrict__ hl2b) {
    int b = blockIdx.x;
    int tid = threadIdx.x;
    if (b < NB_CAST) {
        int i = b * 256 + tid;               // float4 index, exact
        float4 v = reinterpret_cast<const float4*>(x)[i];
        ushort4 o;
        o.x = f2bf(v.x); o.y = f2bf(v.y); o.z = f2bf(v.z); o.w = f2bf(v.w);
        reinterpret_cast<ushort4*>(xb)[i] = o;
    } else if (b < NB_CAST + NB_PREPW) {
        int t = (b - NB_CAST) * 256 + tid;   // 0..16383, exact
        int j = t >> 7, k = t & 127;
        Wc0[j * 256 + k]       = f2bf(Wl0[t]);
        Wc0[j * 256 + 128 + k] = f2bf(Wr0[t]);
        Wc1[j * 256 + k]       = f2bf(Wl1[t]);
        Wc1[j * 256 + 128 + k] = f2bf(Wr1[t]);
    } else if (b < NB_CAST + NB_PREPW + NB_PREPW2) {
        int t = (b - NB_CAST - NB_PREPW) * 256 + tid;  // 0..2047
        int j = t >> 7, k = t & 127;
        Wc2[j * 128 + k]        = f2bf(Wl2[t]);
        Wc2[(16 + j) * 128 + k] = f2bf(Wr2[t]);
    } else if (b < NB_CAST + NB_PREPW + NB_PREPW2 + NB_DEG) {
        int e = (b - NB_CAST - NB_PREPW - NB_PREPW2) * 256 + tid;
        if (e < NE) atomicAdd(&deg[dst[e]], 1);
    } else {
        // zero rows at index NN (targets of padded edges)
        if (tid < DD) { xb[(size_t)NN * DD + tid] = 0; H1[(size_t)NN * DD + tid] = 0; }
        if (tid < 16) hl2b[(size_t)NN * 16 + tid] = 0;
    }
}

// ---------------- CSR build (padded to multiples of 4) ----------------

__global__ __launch_bounds__(256) void k_scan1(const int* __restrict__ deg,
                                               int* __restrict__ bsum,
                                               int* __restrict__ hist) {
    __shared__ int sm[256];
    __shared__ int lh[32];
    int t = threadIdx.x;
    if (t < 32) lh[t] = 0;
    int idx = blockIdx.x * 1024 + t * 4;
    int4 v = make_int4(0, 0, 0, 0);
    if (idx + 3 < NN) v = *reinterpret_cast<const int4*>(deg + idx);
    else {
        if (idx     < NN) v.x = deg[idx];
        if (idx + 1 < NN) v.y = deg[idx + 1];
        if (idx + 2 < NN) v.z = deg[idx + 2];
        if (idx + 3 < NN) v.w = deg[idx + 3];
    }
    int p0 = (v.x + 3) & ~3, p1 = (v.y + 3) & ~3, p2 = (v.z + 3) & ~3, p3 = (v.w + 3) & ~3;
    sm[t] = p0 + p1 + p2 + p3;
    __syncthreads();
    if (idx     < NN) atomicAdd(&lh[min(p0 >> 2, 31)], 1);
    if (idx + 1 < NN) atomicAdd(&lh[min(p1 >> 2, 31)], 1);
    if (idx + 2 < NN) atomicAdd(&lh[min(p2 >> 2, 31)], 1);
    if (idx + 3 < NN) atomicAdd(&lh[min(p3 >> 2, 31)], 1);
    __syncthreads();
    if (t < 32) atomicAdd(&hist[t], lh[t]);
    for (int off = 128; off > 0; off >>= 1) {
        if (t < off) sm[t] += sm[t + off];
        __syncthreads();
    }
    if (t == 0) bsum[blockIdx.x] = sm[0];
}

__global__ __launch_bounds__(128) void k_scan2(int* __restrict__ bsum,
                                               const int* __restrict__ hist,
                                               int* __restrict__ cursor) {
    __shared__ int sm[128];
    int t = threadIdx.x;
    int v = (t < NB_SCAN) ? bsum[t] : 0;
    sm[t] = v;
    __syncthreads();
    for (int off = 1; off < 128; off <<= 1) {
        int add = (t >= off) ? sm[t - off] : 0;
        __syncthreads();
        sm[t] += add;
        __syncthreads();
    }
    if (t < NB_SCAN) bsum[t] = (t == 0) ? 0 : sm[t - 1];  // exclusive, in-place
    if (t == 0) {   // DESCENDING bucket order: heavy blocks dispatched first
        int r = 0;
        for (int c = 31; c >= 0; --c) { cursor[c] = r; r += hist[c]; }
    }
}

// scan3: padded CSR offsets + pad-fill + per-node descriptor (bucketed order)
__global__ __launch_bounds__(256) void k_scan3(const int* __restrict__ deg,
                                               const int* __restrict__ boff,
                                               int* __restrict__ cur,
                                               int* __restrict__ col2,
                                               int* __restrict__ cursor,
                                               int4* __restrict__ desc) {
    __shared__ int sm[256];
    __shared__ int lh[32];
    __shared__ int lb[32];
    int t = threadIdx.x;
    if (t < 32) lh[t] = 0;
    int idx = blockIdx.x * 1024 + t * 4;
    int4 v = make_int4(0, 0, 0, 0);
    if (idx + 3 < NN) v = *reinterpret_cast<const int4*>(deg + idx);
    else {
        if (idx     < NN) v.x = deg[idx];
        if (idx + 1 < NN) v.y = deg[idx + 1];
        if (idx + 2 < NN) v.z = deg[idx + 2];
        if (idx + 3 < NN) v.w = deg[idx + 3];
    }
    int p0 = (v.x + 3) & ~3, p1 = (v.y + 3) & ~3, p2 = (v.z + 3) & ~3, p3 = (v.w + 3) & ~3;
    sm[t] = p0 + p1 + p2 + p3;
    __syncthreads();
    for (int off = 1; off < 256; off <<= 1) {
        int add = (t >= off) ? sm[t - off] : 0;
        __syncthreads();
        sm[t] += add;
        __syncthreads();
    }
    int run = boff[blockIdx.x] + ((t == 0) ? 0 : sm[t - 1]);
    int d[4] = {v.x, v.y, v.z, v.w};
    int p[4] = {p0, p1, p2, p3};
    int begs[4], ci[4], myi[4];
#pragma unroll
    for (int i = 0; i < 4; ++i) {
        if (idx + i < NN) {
            begs[i] = run;
            cur[idx + i] = run;
            for (int q = run + d[i]; q < run + p[i]; ++q) col2[q] = NN;  // pads -> zero row
            ci[i] = min(p[i] >> 2, 31);
            myi[i] = atomicAdd(&lh[ci[i]], 1);
            run += p[i];
        }
    }
    __syncthreads();
    if (t < 32 && lh[t] > 0) lb[t] = atomicAdd(&cursor[t], lh[t]);
    __syncthreads();
#pragma unroll
    for (int i = 0; i < 4; ++i) {
        if (idx + i < NN) {
            float iv = 1.0f / (float)(d[i] > 0 ? d[i] : 1);
            desc[lb[ci[i]] + myi[i]] =
                make_int4(idx + i, begs[i], begs[i] + p[i], __float_as_int(iv));
        }
    }
}

__global__ __launch_bounds__(256) void k_scatter(const int* __restrict__ src,
                                                 const int* __restrict__ dst,
                                                 int* __restrict__ cur,
                                                 int* __restrict__ col2) {
    int e = blockIdx.x * 256 + threadIdx.x;
    if (e < NE) {
        int p = atomicAdd(&cur[dst[e]], 1);
        col2[p] = src[e];
    }
}

// ---------------- fused SAGE layer (layers 0/1) ----------------
// One block = 32 nodes via desc (degree-bucketed, heavy-first), 8 lanes/node.
// Phase 1: mean-gather (4 edges/iter, 8x16B in flight) -> LDS [agg|x] K=256
// swizzled (rows 512B). Phase 2: 4 waves x {2 node-groups x 32 cols}: W-frag
// register reuse x2, 32 MFMAs. Epilogue -> LDS -> full-row stores (STORE) or
// fused W2 transform producing hl2b/hr2 (DOW2, layer 1 -> H2 never hits HBM).

template<bool STORE, bool DOW2>
__global__ __launch_bounds__(256) void k_fused_layer(const u16* __restrict__ X,
                                                     const int* __restrict__ col2,
                                                     const int4* __restrict__ desc,
                                                     const u16* __restrict__ Wc,
                                                     const float* __restrict__ b,
                                                     u16* __restrict__ out,
                                                     const u16* __restrict__ Wc2,
                                                     u16* __restrict__ hl2b,
                                                     float* __restrict__ hr2) {
    __shared__ u16 XK[32 * 256];  // 16 KB; row = local node (512 B), swizzle: byte ^ (r&7)<<4
    char* lds = reinterpret_cast<char*>(XK);

    int tid = threadIdx.x;
    int nl = tid >> 3;     // local node 0..31
    int sl = tid & 7;      // 32B k-slice 0..7
    int4 d = desc[blockIdx.x * 32 + nl];
    int n = d.x, beg = d.y, end = d.z;
    float iv = __int_as_float(d.w);
    int m = (nl & 7) << 4;

    // self row -> LDS bytes [256 + sl*32, +32)
    {
        const u16* xs = X + (size_t)n * DD + sl * 16;
        uint4 s0 = *reinterpret_cast<const uint4*>(xs);
        uint4 s1 = *reinterpret_cast<const uint4*>(xs + 8);
        int boff = 256 + sl * 32;
        *reinterpret_cast<uint4*>(lds + nl * 512 + (boff ^ m)) = s0;
        *reinterpret_cast<uint4*>(lds + nl * 512 + ((boff + 16) ^ m)) = s1;
    }

    // mean-gather: padded list (multiple of 4), 4 edges x 2 uint4 per iter
    float a0 = 0.f, a1 = 0.f, a2 = 0.f, a3 = 0.f, a4 = 0.f, a5 = 0.f, a6 = 0.f, a7 = 0.f;
    float a8 = 0.f, a9 = 0.f, a10 = 0.f, a11 = 0.f, a12 = 0.f, a13 = 0.f, a14 = 0.f, a15 = 0.f;
    for (int e = beg; e < end; e += 4) {
        int4 c = *reinterpret_cast<const int4*>(col2 + e);
        const u16* p0 = X + (size_t)c.x * DD + sl * 16;
        const u16* p1 = X + (size_t)c.y * DD + sl * 16;
        const u16* p2 = X + (size_t)c.z * DD + sl * 16;
        const u16* p3 = X + (size_t)c.w * DD + sl * 16;
        uint4 v0 = *reinterpret_cast<const uint4*>(p0);
        uint4 w0 = *reinterpret_cast<const uint4*>(p0 + 8);
        uint4 v1 = *reinterpret_cast<const uint4*>(p1);
        uint4 w1 = *reinterpret_cast<const uint4*>(p1 + 8);
        uint4 v2 = *reinterpret_cast<const uint4*>(p2);
        uint4 w2 = *reinterpret_cast<const uint4*>(p2 + 8);
        uint4 v3 = *reinterpret_cast<const uint4*>(p3);
        uint4 w3 = *reinterpret_cast<const uint4*>(p3 + 8);
        a0  += (bflo(v0.x) + bflo(v1.x)) + (bflo(v2.x) + bflo(v3.x));
        a1  += (bfhi(v0.x) + bfhi(v1.x)) + (bfhi(v2.x) + bfhi(v3.x));
        a2  += (bflo(v0.y) + bflo(v1.y)) + (bflo(v2.y) + bflo(v3.y));
        a3  += (bfhi(v0.y) + bfhi(v1.y)) + (bfhi(v2.y) + bfhi(v3.y));
        a4  += (bflo(v0.z) + bflo(v1.z)) + (bflo(v2.z) + bflo(v3.z));
        a5  += (bfhi(v0.z) + bfhi(v1.z)) + (bfhi(v2.z) + bfhi(v3.z));
        a6  += (bflo(v0.w) + bflo(v1.w)) + (bflo(v2.w) + bflo(v3.w));
        a7  += (bfhi(v0.w) + bfhi(v1.w)) + (bfhi(v2.w) + bfhi(v3.w));
        a8  += (bflo(w0.x) + bflo(w1.x)) + (bflo(w2.x) + bflo(w3.x));
        a9  += (bfhi(w0.x) + bfhi(w1.x)) + (bfhi(w2.x) + bfhi(w3.x));
        a10 += (bflo(w0.y) + bflo(w1.y)) + (bflo(w2.y) + bflo(w3.y));
        a11 += (bfhi(w0.y) + bfhi(w1.y)) + (bfhi(w2.y) + bfhi(w3.y));
        a12 += (bflo(w0.z) + bflo(w1.z)) + (bflo(w2.z) + bflo(w3.z));
        a13 += (bfhi(w0.z) + bfhi(w1.z)) + (bfhi(w2.z) + bfhi(w3.z));
        a14 += (bflo(w0.w) + bflo(w1.w)) + (bflo(w2.w) + bflo(w3.w));
        a15 += (bfhi(w0.w) + bfhi(w1.w)) + (bfhi(w2.w) + bfhi(w3.w));
    }
    uint4 o0, o1;
    o0.x = (u32)f2bf(a0 * iv)  | ((u32)f2bf(a1 * iv)  << 16);
    o0.y = (u32)f2bf(a2 * iv)  | ((u32)f2bf(a3 * iv)  << 16);
    o0.z = (u32)f2bf(a4 * iv)  | ((u32)f2bf(a5 * iv)  << 16);
    o0.w = (u32)f2bf(a6 * iv)  | ((u32)f2bf(a7 * iv)  << 16);
    o1.x = (u32)f2bf(a8 * iv)  | ((u32)f2bf(a9 * iv)  << 16);
    o1.y = (u32)f2bf(a10 * iv) | ((u32)f2bf(a11 * iv) << 16);
    o1.z = (u32)f2bf(a12 * iv) | ((u32)f2bf(a13 * iv) << 16);
    o1.w = (u32)f2bf(a14 * iv) | ((u32)f2bf(a15 * iv) << 16);
    *reinterpret_cast<uint4*>(lds + nl * 512 + ((sl * 32) ^ m)) = o0;
    *reinterpret_cast<uint4*>(lds + nl * 512 + ((sl * 32 + 16) ^ m)) = o1;
    __syncthreads();

    // ---- phase 2: GEMM (W-frag reused across 2 node-groups) ----
    int wid = tid >> 6, lane = tid & 63;
    int cl = lane & 15, rq = lane >> 4;
    int xm = (cl & 7) << 4;

    f32x4 acc00 = (f32x4){0.f, 0.f, 0.f, 0.f};
    f32x4 acc01 = (f32x4){0.f, 0.f, 0.f, 0.f};
    f32x4 acc10 = (f32x4){0.f, 0.f, 0.f, 0.f};
    f32x4 acc11 = (f32x4){0.f, 0.f, 0.f, 0.f};
    const u16* wbase = Wc + (size_t)(wid * 32 + cl) * 256 + rq * 8;
    const char* x0b = lds + cl * 512;
    const char* x1b = lds + (16 + cl) * 512;
#pragma unroll
    for (int ks = 0; ks < 8; ++ks) {
        int xo = (ks * 64 + rq * 16) ^ xm;
        bf16x8 xf0 = *reinterpret_cast<const bf16x8*>(x0b + xo);
        bf16x8 xf1 = *reinterpret_cast<const bf16x8*>(x1b + xo);
        bf16x8 wf0 = *reinterpret_cast<const bf16x8*>(wbase + ks * 32);
        bf16x8 wf1 = *reinterpret_cast<const bf16x8*>(wbase + 16 * 256 + ks * 32);
        acc00 = __builtin_amdgcn_mfma_f32_16x16x32_bf16(wf0, xf0, acc00, 0, 0, 0);
        acc01 = __builtin_amdgcn_mfma_f32_16x16x32_bf16(wf1, xf0, acc01, 0, 0, 0);
        acc10 = __builtin_amdgcn_mfma_f32_16x16x32_bf16(wf0, xf1, acc10, 0, 0, 0);
        acc11 = __builtin_amdgcn_mfma_f32_16x16x32_bf16(wf1, xf1, acc11, 0, 0, 0);
    }
    __syncthreads();   // XK reads done; safe to overwrite with output tile

    // bias + relu + pack -> LDS (node-row g*16+cl, col bytes (j*2)^swz)
#pragma unroll
    for (int g = 0; g < 2; ++g) {
#pragma unroll
        for (int jf = 0; jf < 2; ++jf) {
            f32x4 a = g ? (jf ? acc11 : acc10) : (jf ? acc01 : acc00);
            int j0 = wid * 32 + jf * 16 + rq * 4;
            float4 bias = *reinterpret_cast<const float4*>(b + j0);
            float o0f = fmaxf(a[0] + bias.x, 0.f);
            float o1f = fmaxf(a[1] + bias.y, 0.f);
            float o2f = fmaxf(a[2] + bias.z, 0.f);
            float o3f = fmaxf(a[3] + bias.w, 0.f);
            uint2 pk;
            pk.x = (u32)f2bf(o0f) | ((u32)f2bf(o1f) << 16);
            pk.y = (u32)f2bf(o2f) | ((u32)f2bf(o3f) << 16);
            int row = g * 16 + cl;
            *reinterpret_cast<uint2*>(lds + row * 512 + ((j0 * 2) ^ ((cl & 7) << 4))) = pk;
        }
    }
    __syncthreads();

    if (STORE) {
        // full-row stores: thread (nl, sl) stores bytes [sl*32, +32) of row n
        uint4 q0 = *reinterpret_cast<const uint4*>(lds + nl * 512 + ((sl * 32) ^ m));
        uint4 q1 = *reinterpret_cast<const uint4*>(lds + nl * 512 + ((sl * 32 + 16) ^ m));
        u16* orow = out + (size_t)n * DD + sl * 16;
        *reinterpret_cast<uint4*>(orow) = q0;
        *reinterpret_cast<uint4*>(orow + 8) = q1;
    }

    if (DOW2) {
        // fused layer-2 transforms from the LDS output tile (K=128)
        int g = wid >> 1, tbl = wid & 1;
        f32x4 a2 = (f32x4){0.f, 0.f, 0.f, 0.f};
        const u16* wb = Wc2 + (size_t)(tbl * 16 + cl) * 128 + rq * 8;
        const char* xb = lds + (size_t)(g * 16 + cl) * 512;
#pragma unroll
        for (int ks = 0; ks < 4; ++ks) {
            bf16x8 xf = *reinterpret_cast<const bf16x8*>(xb + ((ks * 64 + rq * 16) ^ xm));
            bf16x8 wf = *reinterpret_cast<const bf16x8*>(wb + ks * 32);
            a2 = __builtin_amdgcn_mfma_f32_16x16x32_bf16(wf, xf, a2, 0, 0, 0);
        }
        int n2 = desc[blockIdx.x * 32 + g * 16 + cl].x;
        if (tbl == 0) {
            uint2 pk;
            pk.x = (u32)f2bf(a2[0]) | ((u32)f2bf(a2[1]) << 16);
            pk.y = (u32)f2bf(a2[2]) | ((u32)f2bf(a2[3]) << 16);
            *reinterpret_cast<uint2*>(hl2b + (size_t)n2 * 16 + rq * 4) = pk;
        } else {
            *reinterpret_cast<float4*>(hr2 + (size_t)n2 * 16 + rq * 4) =
                make_float4(a2[0], a2[1], a2[2], a2[3]);
        }
    }
}

// ---------------- layer 2 final ----------------

// k_l2_final: 8 lanes/node mean-gather(hl2b) + hr2 + bias -> log_softmax.
__global__ __launch_bounds__(256) void k_l2_final(const u16* __restrict__ hl2b,
                                                  const float* __restrict__ hr2,
                                                  const int* __restrict__ col2,
                                                  const int4* __restrict__ desc,
                                                  const float* __restrict__ b2,
                                                  float* __restrict__ out) {
    int tid = threadIdx.x;
    int ns = tid >> 3;   // node slot 0..31
    int l  = tid & 7;
    int4 d = desc[blockIdx.x * 32 + ns];
    int n = d.x, beg = d.y, end = d.z;
    float iv = __int_as_float(d.w);

    float ag[16];
#pragma unroll
    for (int j = 0; j < 16; ++j) ag[j] = 0.f;
    for (int e = beg + l; e < end; e += 8) {
        const u16* r = hl2b + (size_t)col2[e] * 16;
        uint4 h0 = *reinterpret_cast<const uint4*>(r);
        uint4 h1 = *reinterpret_cast<const uint4*>(r + 8);
        ag[0] += bflo(h0.x); ag[1] += bfhi(h0.x); ag[2]  += bflo(h0.y); ag[3]  += bfhi(h0.y);
        ag[4] += bflo(h0.z); ag[5] += bfhi(h0.z); ag[6]  += bflo(h0.w); ag[7]  += bfhi(h0.w);
        ag[8] += bflo(h1.x); ag[9] += bfhi(h1.x); ag[10] += bflo(h1.y); ag[11] += bfhi(h1.y);
        ag[12] += bflo(h1.z); ag[13] += bfhi(h1.z); ag[14] += bflo(h1.w); ag[15] += bfhi(h1.w);
    }
#pragma unroll
    for (int m = 1; m <= 4; m <<= 1) {
#pragma unroll
        for (int j = 0; j < 16; ++j) ag[j] += __shfl_xor(ag[j], m);
    }
    if (l < 4) {
        float4 hr = *reinterpret_cast<const float4*>(hr2 + (size_t)n * 16 + l * 4);
        float4 bb = *reinterpret_cast<const float4*>(b2 + l * 4);
        float v0 = hr.x + bb.x + ag[l * 4 + 0] * iv;
        float v1 = hr.y + bb.y + ag[l * 4 + 1] * iv;
        float v2 = hr.z + bb.z + ag[l * 4 + 2] * iv;
        float v3 = hr.w + bb.w + ag[l * 4 + 3] * iv;
        float m4 = fmaxf(fmaxf(v0, v1), fmaxf(v2, v3));
        m4 = fmaxf(m4, __shfl_xor(m4, 1));
        m4 = fmaxf(m4, __shfl_xor(m4, 2));
        float s4 = expf(v0 - m4) + expf(v1 - m4) + expf(v2 - m4) + expf(v3 - m4);
        s4 += __shfl_xor(s4, 1);
        s4 += __shfl_xor(s4, 2);
        float lse = m4 + logf(s4);
        *reinterpret_cast<float4*>(out + (size_t)n * 16 + l * 4) =
            make_float4(v0 - lse, v1 - lse, v2 - lse, v3 - lse);
    }
}

// ---------------- host launcher ----------------

extern "C" void kernel_launch(void* const* d_in, const int* in_sizes, int n_in,
                              void* d_out, int out_size, void* d_ws, size_t ws_size,
                              hipStream_t stream) {
    const float* x   = (const float*)d_in[0];
    const int*   ei  = (const int*)d_in[1];
    const float* Wl0 = (const float*)d_in[2];
    const float* bl0 = (const float*)d_in[3];
    const float* Wr0 = (const float*)d_in[4];
    const float* Wl1 = (const float*)d_in[5];
    const float* bl1 = (const float*)d_in[6];
    const float* Wr1 = (const float*)d_in[7];
    const float* Wl2 = (const float*)d_in[8];
    const float* bl2 = (const float*)d_in[9];
    const float* Wr2 = (const float*)d_in[10];
    float* out = (float*)d_out;

    const int* e_src = ei;       // edge_index[0]
    const int* e_dst = ei + NE;  // edge_index[1]

    // workspace carve-out (256B aligned)
    char* ws = (char*)d_ws;
    size_t off = 0;
    auto carve = [&](size_t bytes) -> void* {
        void* p = ws + off;
        off = (off + bytes + 255) & ~(size_t)255;
        return p;
    };
    int*   deg  = (int*)carve((size_t)(NN + 128) * 4);  // deg | hist(32) | cursor(32)
    int*   hist = deg + NN;
    int*   curs = deg + NN + 32;
    int*   cur  = (int*)carve((size_t)NN * 4);
    int*   bsum = (int*)carve(512 * 4);
    int*   col2 = (int*)carve((size_t)(NE + 3 * NN + 64) * 4);  // padded CSR
    int4*  desc = (int4*)carve((size_t)NN * 16);
    u16*   xb   = (u16*)carve((size_t)(NN + 1) * DD * 2);       // +1: zero row
    u16*   H1   = (u16*)carve((size_t)(NN + 1) * DD * 2);       // +1: zero row
    u16*   Wc0  = (u16*)carve((size_t)128 * 256 * 2);
    u16*   Wc1  = (u16*)carve((size_t)128 * 256 * 2);
    u16*   Wc2  = (u16*)carve((size_t)32 * 128 * 2);
    u16*   hl2b = (u16*)carve((size_t)(NN + 1) * 16 * 2);       // +1: zero row
    float* hr2  = (float*)carve((size_t)NN * 16 * 4);
    (void)ws_size; (void)in_sizes; (void)n_in; (void)out_size;

    // setup: zero {deg|hist|cursor}, then sectioned prep
    hipMemsetAsync(deg, 0, (size_t)(NN + 128) * 4, stream);
    k_setup<<<NB_CAST + NB_PREPW + NB_PREPW2 + NB_DEG + 1, 256, 0, stream>>>(
        x, xb, Wl0, Wr0, Wl1, Wr1, Wl2, Wr2, Wc0, Wc1, Wc2, e_dst, deg, H1, hl2b);

    // padded CSR + descriptor (degree-bucketed, heavy-first)
    k_scan1<<<NB_SCAN, 256, 0, stream>>>(deg, bsum, hist);
    k_scan2<<<1, 128, 0, stream>>>(bsum, hist, curs);
    k_scan3<<<NB_SCAN, 256, 0, stream>>>(deg, bsum, cur, col2, curs, desc);
    k_scatter<<<(NE + 255) / 256, 256, 0, stream>>>(e_src, e_dst, cur, col2);

    // layer 0: H1 = relu([gather(xb)|xb]@Wc0 + bl0)
    k_fused_layer<true, false><<<NN / 32, 256, 0, stream>>>(
        xb, col2, desc, Wc0, bl0, H1, nullptr, nullptr, nullptr);

    // layer 1 + fused layer-2 transforms (H2 stays in LDS; hl2b/hr2 out)
    k_fused_layer<false, true><<<NN / 32, 256, 0, stream>>>(
        H1, col2, desc, Wc1, bl1, nullptr, Wc2, hl2b, hr2);

    // layer 2 final: fused mean-gather + log_softmax
    k_l2_final<<<NN / 32, 256, 0, stream>>>(hl2b, hr2, col2, desc, bl2, out);
}

// Round 11
// 196.711 us; speedup vs baseline: 1.4771x; 1.0322x over previous
//
#include <hip/hip_runtime.h>
#include <math.h>

#define NN 100000   // nodes
#define NE 600000   // edges
#define DD 128      // hidden dim
#define NB_SCAN 98  // ceil(NN/1024)

// k_setup grid sections
#define NB_CAST 12500   // NN*32 float4s / 256
#define NB_PREPW 64     // 128*128 / 256
#define NB_PREPW2 8     // 16*128 / 256
#define NB_DEG 2344     // ceil(NE/256)

typedef __attribute__((ext_vector_type(8))) short bf16x8;
typedef __attribute__((ext_vector_type(4))) float f32x4;
typedef __attribute__((ext_vector_type(4))) unsigned int u32x4;  // clang vector for NT stores
typedef unsigned short u16;
typedef unsigned int u32;

__device__ __forceinline__ float bflo(u32 w) {
    union { u32 i; float f; } v; v.i = w << 16; return v.f;
}
__device__ __forceinline__ float bfhi(u32 w) {
    union { u32 i; float f; } v; v.i = w & 0xffff0000u; return v.f;
}
__device__ __forceinline__ u16 f2bf(float f) {
    union { float f; u32 u; } v; v.f = f;
    u32 r = v.u + 0x7fffu + ((v.u >> 16) & 1u);  // RNE
    return (u16)(r >> 16);
}

// ---------------- setup: cast + weight prep + degree + zero-rows ----------

__global__ __launch_bounds__(256) void k_setup(const float* __restrict__ x,
                                               u16* __restrict__ xb,
                                               const float* __restrict__ Wl0,
                                               const float* __restrict__ Wr0,
                                               const float* __restrict__ Wl1,
                                               const float* __restrict__ Wr1,
                                               const float* __restrict__ Wl2,
                                               const float* __restrict__ Wr2,
                                               u16* __restrict__ Wc0,
                                               u16* __restrict__ Wc1,
                                               u16* __restrict__ Wc2,
                                               const int* __restrict__ dst,
                                               int* __restrict__ deg,
                                               u16* __restrict__ H1,
                                               u16* __restrict__ hl2b) {
    int b = blockIdx.x;
    int tid = threadIdx.x;
    if (b < NB_CAST) {
        int i = b * 256 + tid;               // float4 index, exact
        float4 v = reinterpret_cast<const float4*>(x)[i];
        ushort4 o;
        o.x = f2bf(v.x); o.y = f2bf(v.y); o.z = f2bf(v.z); o.w = f2bf(v.w);
        reinterpret_cast<ushort4*>(xb)[i] = o;
    } else if (b < NB_CAST + NB_PREPW) {
        int t = (b - NB_CAST) * 256 + tid;   // 0..16383, exact
        int j = t >> 7, k = t & 127;
        Wc0[j * 256 + k]       = f2bf(Wl0[t]);
        Wc0[j * 256 + 128 + k] = f2bf(Wr0[t]);
        Wc1[j * 256 + k]       = f2bf(Wl1[t]);
        Wc1[j * 256 + 128 + k] = f2bf(Wr1[t]);
    } else if (b < NB_CAST + NB_PREPW + NB_PREPW2) {
        int t = (b - NB_CAST - NB_PREPW) * 256 + tid;  // 0..2047
        int j = t >> 7, k = t & 127;
        Wc2[j * 128 + k]        = f2bf(Wl2[t]);
        Wc2[(16 + j) * 128 + k] = f2bf(Wr2[t]);
    } else if (b < NB_CAST + NB_PREPW + NB_PREPW2 + NB_DEG) {
        int e = (b - NB_CAST - NB_PREPW - NB_PREPW2) * 256 + tid;
        if (e < NE) atomicAdd(&deg[dst[e]], 1);
    } else {
        // zero rows at index NN (targets of padded edges)
        if (tid < DD) { xb[(size_t)NN * DD + tid] = 0; H1[(size_t)NN * DD + tid] = 0; }
        if (tid < 16) hl2b[(size_t)NN * 16 + tid] = 0;
    }
}

// ---------------- CSR build (padded to multiples of 4) ----------------

__global__ __launch_bounds__(256) void k_scan1(const int* __restrict__ deg,
                                               int* __restrict__ bsum,
                                               int* __restrict__ hist) {
    __shared__ int sm[256];
    __shared__ int lh[32];
    int t = threadIdx.x;
    if (t < 32) lh[t] = 0;
    int idx = blockIdx.x * 1024 + t * 4;
    int4 v = make_int4(0, 0, 0, 0);
    if (idx + 3 < NN) v = *reinterpret_cast<const int4*>(deg + idx);
    else {
        if (idx     < NN) v.x = deg[idx];
        if (idx + 1 < NN) v.y = deg[idx + 1];
        if (idx + 2 < NN) v.z = deg[idx + 2];
        if (idx + 3 < NN) v.w = deg[idx + 3];
    }
    int p0 = (v.x + 3) & ~3, p1 = (v.y + 3) & ~3, p2 = (v.z + 3) & ~3, p3 = (v.w + 3) & ~3;
    sm[t] = p0 + p1 + p2 + p3;
    __syncthreads();
    if (idx     < NN) atomicAdd(&lh[min(p0 >> 2, 31)], 1);
    if (idx + 1 < NN) atomicAdd(&lh[min(p1 >> 2, 31)], 1);
    if (idx + 2 < NN) atomicAdd(&lh[min(p2 >> 2, 31)], 1);
    if (idx + 3 < NN) atomicAdd(&lh[min(p3 >> 2, 31)], 1);
    __syncthreads();
    if (t < 32) atomicAdd(&hist[t], lh[t]);
    for (int off = 128; off > 0; off >>= 1) {
        if (t < off) sm[t] += sm[t + off];
        __syncthreads();
    }
    if (t == 0) bsum[blockIdx.x] = sm[0];
}

__global__ __launch_bounds__(128) void k_scan2(int* __restrict__ bsum,
                                               const int* __restrict__ hist,
                                               int* __restrict__ cursor) {
    __shared__ int sm[128];
    int t = threadIdx.x;
    int v = (t < NB_SCAN) ? bsum[t] : 0;
    sm[t] = v;
    __syncthreads();
    for (int off = 1; off < 128; off <<= 1) {
        int add = (t >= off) ? sm[t - off] : 0;
        __syncthreads();
        sm[t] += add;
        __syncthreads();
    }
    if (t < NB_SCAN) bsum[t] = (t == 0) ? 0 : sm[t - 1];  // exclusive, in-place
    if (t == 0) {   // DESCENDING bucket order: heavy blocks dispatched first
        int r = 0;
        for (int c = 31; c >= 0; --c) { cursor[c] = r; r += hist[c]; }
    }
}

// scan3: padded CSR offsets + pad-fill + per-node descriptor (bucketed order)
__global__ __launch_bounds__(256) void k_scan3(const int* __restrict__ deg,
                                               const int* __restrict__ boff,
                                               int* __restrict__ cur,
                                               int* __restrict__ col2,
                                               int* __restrict__ cursor,
                                               int4* __restrict__ desc) {
    __shared__ int sm[256];
    __shared__ int lh[32];
    __shared__ int lb[32];
    int t = threadIdx.x;
    if (t < 32) lh[t] = 0;
    int idx = blockIdx.x * 1024 + t * 4;
    int4 v = make_int4(0, 0, 0, 0);
    if (idx + 3 < NN) v = *reinterpret_cast<const int4*>(deg + idx);
    else {
        if (idx     < NN) v.x = deg[idx];
        if (idx + 1 < NN) v.y = deg[idx + 1];
        if (idx + 2 < NN) v.z = deg[idx + 2];
        if (idx + 3 < NN) v.w = deg[idx + 3];
    }
    int p0 = (v.x + 3) & ~3, p1 = (v.y + 3) & ~3, p2 = (v.z + 3) & ~3, p3 = (v.w + 3) & ~3;
    sm[t] = p0 + p1 + p2 + p3;
    __syncthreads();
    for (int off = 1; off < 256; off <<= 1) {
        int add = (t >= off) ? sm[t - off] : 0;
        __syncthreads();
        sm[t] += add;
        __syncthreads();
    }
    int run = boff[blockIdx.x] + ((t == 0) ? 0 : sm[t - 1]);
    int d[4] = {v.x, v.y, v.z, v.w};
    int p[4] = {p0, p1, p2, p3};
    int begs[4], ci[4], myi[4];
#pragma unroll
    for (int i = 0; i < 4; ++i) {
        if (idx + i < NN) {
            begs[i] = run;
            cur[idx + i] = run;
            for (int q = run + d[i]; q < run + p[i]; ++q) col2[q] = NN;  // pads -> zero row
            ci[i] = min(p[i] >> 2, 31);
            myi[i] = atomicAdd(&lh[ci[i]], 1);
            run += p[i];
        }
    }
    __syncthreads();
    if (t < 32 && lh[t] > 0) lb[t] = atomicAdd(&cursor[t], lh[t]);
    __syncthreads();
#pragma unroll
    for (int i = 0; i < 4; ++i) {
        if (idx + i < NN) {
            float iv = 1.0f / (float)(d[i] > 0 ? d[i] : 1);
            desc[lb[ci[i]] + myi[i]] =
                make_int4(idx + i, begs[i], begs[i] + p[i], __float_as_int(iv));
        }
    }
}

__global__ __launch_bounds__(256) void k_scatter(const int* __restrict__ src,
                                                 const int* __restrict__ dst,
                                                 int* __restrict__ cur,
                                                 int* __restrict__ col2) {
    int e = blockIdx.x * 256 + threadIdx.x;
    if (e < NE) {
        int p = atomicAdd(&cur[dst[e]], 1);
        col2[p] = src[e];
    }
}

// ---------------- fused SAGE layer (layers 0/1) ----------------
// One block = 32 nodes via desc (degree-bucketed, heavy-first), 8 lanes/node.
// Phase 1: mean-gather with col-index prefetch pipeline -> LDS [agg|x] K=256
// swizzled (rows 512B). Phase 2: 4 waves x {2 node-groups x 32 cols}: W-frag
// register reuse x2, 32 MFMAs. Epilogue -> LDS -> full-row NT stores (STORE)
// or fused W2 transform producing hl2b/hr2 (DOW2; H2 never hits HBM).

template<bool STORE, bool DOW2>
__global__ __launch_bounds__(256) void k_fused_layer(const u16* __restrict__ X,
                                                     const int* __restrict__ col2,
                                                     const int4* __restrict__ desc,
                                                     const u16* __restrict__ Wc,
                                                     const float* __restrict__ b,
                                                     u16* __restrict__ out,
                                                     const u16* __restrict__ Wc2,
                                                     u16* __restrict__ hl2b,
                                                     float* __restrict__ hr2) {
    __shared__ u16 XK[32 * 256];  // 16 KB; row = local node (512 B), swizzle: byte ^ (r&7)<<4
    char* lds = reinterpret_cast<char*>(XK);

    int tid = threadIdx.x;
    int nl = tid >> 3;     // local node 0..31
    int sl = tid & 7;      // 32B k-slice 0..7
    int4 d = desc[blockIdx.x * 32 + nl];
    int n = d.x, beg = d.y, end = d.z;
    float iv = __int_as_float(d.w);
    int m = (nl & 7) << 4;

    // first col quad as early as possible (starts the pointer chain)
    int4 c = make_int4(NN, NN, NN, NN);
    if (beg < end) c = *reinterpret_cast<const int4*>(col2 + beg);

    // self row -> LDS bytes [256 + sl*32, +32)
    {
        const u16* xs = X + (size_t)n * DD + sl * 16;
        uint4 s0 = *reinterpret_cast<const uint4*>(xs);
        uint4 s1 = *reinterpret_cast<const uint4*>(xs + 8);
        int boff = 256 + sl * 32;
        *reinterpret_cast<uint4*>(lds + nl * 512 + (boff ^ m)) = s0;
        *reinterpret_cast<uint4*>(lds + nl * 512 + ((boff + 16) ^ m)) = s1;
    }

    // mean-gather: padded list (multiple of 4), col prefetch pipeline
    float a0 = 0.f, a1 = 0.f, a2 = 0.f, a3 = 0.f, a4 = 0.f, a5 = 0.f, a6 = 0.f, a7 = 0.f;
    float a8 = 0.f, a9 = 0.f, a10 = 0.f, a11 = 0.f, a12 = 0.f, a13 = 0.f, a14 = 0.f, a15 = 0.f;
    for (int e = beg; e < end; e += 4) {
        int4 cn = make_int4(NN, NN, NN, NN);
        if (e + 4 < end) cn = *reinterpret_cast<const int4*>(col2 + e + 4);
        const u16* p0 = X + (size_t)c.x * DD + sl * 16;
        const u16* p1 = X + (size_t)c.y * DD + sl * 16;
        const u16* p2 = X + (size_t)c.z * DD + sl * 16;
        const u16* p3 = X + (size_t)c.w * DD + sl * 16;
        uint4 v0 = *reinterpret_cast<const uint4*>(p0);
        uint4 w0 = *reinterpret_cast<const uint4*>(p0 + 8);
        uint4 v1 = *reinterpret_cast<const uint4*>(p1);
        uint4 w1 = *reinterpret_cast<const uint4*>(p1 + 8);
        uint4 v2 = *reinterpret_cast<const uint4*>(p2);
        uint4 w2 = *reinterpret_cast<const uint4*>(p2 + 8);
        uint4 v3 = *reinterpret_cast<const uint4*>(p3);
        uint4 w3 = *reinterpret_cast<const uint4*>(p3 + 8);
        a0  += (bflo(v0.x) + bflo(v1.x)) + (bflo(v2.x) + bflo(v3.x));
        a1  += (bfhi(v0.x) + bfhi(v1.x)) + (bfhi(v2.x) + bfhi(v3.x));
        a2  += (bflo(v0.y) + bflo(v1.y)) + (bflo(v2.y) + bflo(v3.y));
        a3  += (bfhi(v0.y) + bfhi(v1.y)) + (bfhi(v2.y) + bfhi(v3.y));
        a4  += (bflo(v0.z) + bflo(v1.z)) + (bflo(v2.z) + bflo(v3.z));
        a5  += (bfhi(v0.z) + bfhi(v1.z)) + (bfhi(v2.z) + bfhi(v3.z));
        a6  += (bflo(v0.w) + bflo(v1.w)) + (bflo(v2.w) + bflo(v3.w));
        a7  += (bfhi(v0.w) + bfhi(v1.w)) + (bfhi(v2.w) + bfhi(v3.w));
        a8  += (bflo(w0.x) + bflo(w1.x)) + (bflo(w2.x) + bflo(w3.x));
        a9  += (bfhi(w0.x) + bfhi(w1.x)) + (bfhi(w2.x) + bfhi(w3.x));
        a10 += (bflo(w0.y) + bflo(w1.y)) + (bflo(w2.y) + bflo(w3.y));
        a11 += (bfhi(w0.y) + bfhi(w1.y)) + (bfhi(w2.y) + bfhi(w3.y));
        a12 += (bflo(w0.z) + bflo(w1.z)) + (bflo(w2.z) + bflo(w3.z));
        a13 += (bfhi(w0.z) + bfhi(w1.z)) + (bfhi(w2.z) + bfhi(w3.z));
        a14 += (bflo(w0.w) + bflo(w1.w)) + (bflo(w2.w) + bflo(w3.w));
        a15 += (bfhi(w0.w) + bfhi(w1.w)) + (bfhi(w2.w) + bfhi(w3.w));
        c = cn;
    }
    uint4 o0, o1;
    o0.x = (u32)f2bf(a0 * iv)  | ((u32)f2bf(a1 * iv)  << 16);
    o0.y = (u32)f2bf(a2 * iv)  | ((u32)f2bf(a3 * iv)  << 16);
    o0.z = (u32)f2bf(a4 * iv)  | ((u32)f2bf(a5 * iv)  << 16);
    o0.w = (u32)f2bf(a6 * iv)  | ((u32)f2bf(a7 * iv)  << 16);
    o1.x = (u32)f2bf(a8 * iv)  | ((u32)f2bf(a9 * iv)  << 16);
    o1.y = (u32)f2bf(a10 * iv) | ((u32)f2bf(a11 * iv) << 16);
    o1.z = (u32)f2bf(a12 * iv) | ((u32)f2bf(a13 * iv) << 16);
    o1.w = (u32)f2bf(a14 * iv) | ((u32)f2bf(a15 * iv) << 16);
    *reinterpret_cast<uint4*>(lds + nl * 512 + ((sl * 32) ^ m)) = o0;
    *reinterpret_cast<uint4*>(lds + nl * 512 + ((sl * 32 + 16) ^ m)) = o1;
    __syncthreads();

    // ---- phase 2: GEMM (W-frag reused across 2 node-groups) ----
    int wid = tid >> 6, lane = tid & 63;
    int cl = lane & 15, rq = lane >> 4;
    int xm = (cl & 7) << 4;

    f32x4 acc00 = (f32x4){0.f, 0.f, 0.f, 0.f};
    f32x4 acc01 = (f32x4){0.f, 0.f, 0.f, 0.f};
    f32x4 acc10 = (f32x4){0.f, 0.f, 0.f, 0.f};
    f32x4 acc11 = (f32x4){0.f, 0.f, 0.f, 0.f};
    const u16* wbase = Wc + (size_t)(wid * 32 + cl) * 256 + rq * 8;
    const char* x0b = lds + cl * 512;
    const char* x1b = lds + (16 + cl) * 512;
#pragma unroll
    for (int ks = 0; ks < 8; ++ks) {
        int xo = (ks * 64 + rq * 16) ^ xm;
        bf16x8 xf0 = *reinterpret_cast<const bf16x8*>(x0b + xo);
        bf16x8 xf1 = *reinterpret_cast<const bf16x8*>(x1b + xo);
        bf16x8 wf0 = *reinterpret_cast<const bf16x8*>(wbase + ks * 32);
        bf16x8 wf1 = *reinterpret_cast<const bf16x8*>(wbase + 16 * 256 + ks * 32);
        acc00 = __builtin_amdgcn_mfma_f32_16x16x32_bf16(wf0, xf0, acc00, 0, 0, 0);
        acc01 = __builtin_amdgcn_mfma_f32_16x16x32_bf16(wf1, xf0, acc01, 0, 0, 0);
        acc10 = __builtin_amdgcn_mfma_f32_16x16x32_bf16(wf0, xf1, acc10, 0, 0, 0);
        acc11 = __builtin_amdgcn_mfma_f32_16x16x32_bf16(wf1, xf1, acc11, 0, 0, 0);
    }
    __syncthreads();   // XK reads done; safe to overwrite with output tile

    // bias + relu + pack -> LDS (node-row g*16+cl, col bytes (j*2)^swz)
#pragma unroll
    for (int g = 0; g < 2; ++g) {
#pragma unroll
        for (int jf = 0; jf < 2; ++jf) {
            f32x4 a = g ? (jf ? acc11 : acc10) : (jf ? acc01 : acc00);
            int j0 = wid * 32 + jf * 16 + rq * 4;
            float4 bias = *reinterpret_cast<const float4*>(b + j0);
            float o0f = fmaxf(a[0] + bias.x, 0.f);
            float o1f = fmaxf(a[1] + bias.y, 0.f);
            float o2f = fmaxf(a[2] + bias.z, 0.f);
            float o3f = fmaxf(a[3] + bias.w, 0.f);
            uint2 pk;
            pk.x = (u32)f2bf(o0f) | ((u32)f2bf(o1f) << 16);
            pk.y = (u32)f2bf(o2f) | ((u32)f2bf(o3f) << 16);
            int row = g * 16 + cl;
            *reinterpret_cast<uint2*>(lds + row * 512 + ((j0 * 2) ^ ((cl & 7) << 4))) = pk;
        }
    }
    __syncthreads();

    if (STORE) {
        // full-row NT stores (don't evict the gather table from L2):
        // thread (nl, sl) stores bytes [sl*32, +32) of row n
        u32x4 q0 = *reinterpret_cast<const u32x4*>(lds + nl * 512 + ((sl * 32) ^ m));
        u32x4 q1 = *reinterpret_cast<const u32x4*>(lds + nl * 512 + ((sl * 32 + 16) ^ m));
        u32x4* orow = reinterpret_cast<u32x4*>(out + (size_t)n * DD + sl * 16);
        __builtin_nontemporal_store(q0, orow);
        __builtin_nontemporal_store(q1, orow + 1);
    }

    if (DOW2) {
        // fused layer-2 transforms from the LDS output tile (K=128)
        int g = wid >> 1, tbl = wid & 1;
        f32x4 a2 = (f32x4){0.f, 0.f, 0.f, 0.f};
        const u16* wb = Wc2 + (size_t)(tbl * 16 + cl) * 128 + rq * 8;
        const char* xb = lds + (size_t)(g * 16 + cl) * 512;
#pragma unroll
        for (int ks = 0; ks < 4; ++ks) {
            bf16x8 xf = *reinterpret_cast<const bf16x8*>(xb + ((ks * 64 + rq * 16) ^ xm));
            bf16x8 wf = *reinterpret_cast<const bf16x8*>(wb + ks * 32);
            a2 = __builtin_amdgcn_mfma_f32_16x16x32_bf16(wf, xf, a2, 0, 0, 0);
        }
        int n2 = desc[blockIdx.x * 32 + g * 16 + cl].x;
        if (tbl == 0) {
            uint2 pk;
            pk.x = (u32)f2bf(a2[0]) | ((u32)f2bf(a2[1]) << 16);
            pk.y = (u32)f2bf(a2[2]) | ((u32)f2bf(a2[3]) << 16);
            *reinterpret_cast<uint2*>(hl2b + (size_t)n2 * 16 + rq * 4) = pk;
        } else {
            *reinterpret_cast<float4*>(hr2 + (size_t)n2 * 16 + rq * 4) =
                make_float4(a2[0], a2[1], a2[2], a2[3]);
        }
    }
}

// ---------------- layer 2 final ----------------

// k_l2_final: 8 lanes/node mean-gather(hl2b) + hr2 + bias -> log_softmax.
__global__ __launch_bounds__(256) void k_l2_final(const u16* __restrict__ hl2b,
                                                  const float* __restrict__ hr2,
                                                  const int* __restrict__ col2,
                                                  const int4* __restrict__ desc,
                                                  const float* __restrict__ b2,
                                                  float* __restrict__ out) {
    int tid = threadIdx.x;
    int ns = tid >> 3;   // node slot 0..31
    int l  = tid & 7;
    int4 d = desc[blockIdx.x * 32 + ns];
    int n = d.x, beg = d.y, end = d.z;
    float iv = __int_as_float(d.w);

    float ag[16];
#pragma unroll
    for (int j = 0; j < 16; ++j) ag[j] = 0.f;
    for (int e = beg + l; e < end; e += 8) {
        const u16* r = hl2b + (size_t)col2[e] * 16;
        uint4 h0 = *reinterpret_cast<const uint4*>(r);
        uint4 h1 = *reinterpret_cast<const uint4*>(r + 8);
        ag[0] += bflo(h0.x); ag[1] += bfhi(h0.x); ag[2]  += bflo(h0.y); ag[3]  += bfhi(h0.y);
        ag[4] += bflo(h0.z); ag[5] += bfhi(h0.z); ag[6]  += bflo(h0.w); ag[7]  += bfhi(h0.w);
        ag[8] += bflo(h1.x); ag[9] += bfhi(h1.x); ag[10] += bflo(h1.y); ag[11] += bfhi(h1.y);
        ag[12] += bflo(h1.z); ag[13] += bfhi(h1.z); ag[14] += bflo(h1.w); ag[15] += bfhi(h1.w);
    }
#pragma unroll
    for (int m = 1; m <= 4; m <<= 1) {
#pragma unroll
        for (int j = 0; j < 16; ++j) ag[j] += __shfl_xor(ag[j], m);
    }
    if (l < 4) {
        float4 hr = *reinterpret_cast<const float4*>(hr2 + (size_t)n * 16 + l * 4);
        float4 bb = *reinterpret_cast<const float4*>(b2 + l * 4);
        float v0 = hr.x + bb.x + ag[l * 4 + 0] * iv;
        float v1 = hr.y + bb.y + ag[l * 4 + 1] * iv;
        float v2 = hr.z + bb.z + ag[l * 4 + 2] * iv;
        float v3 = hr.w + bb.w + ag[l * 4 + 3] * iv;
        float m4 = fmaxf(fmaxf(v0, v1), fmaxf(v2, v3));
        m4 = fmaxf(m4, __shfl_xor(m4, 1));
        m4 = fmaxf(m4, __shfl_xor(m4, 2));
        float s4 = expf(v0 - m4) + expf(v1 - m4) + expf(v2 - m4) + expf(v3 - m4);
        s4 += __shfl_xor(s4, 1);
        s4 += __shfl_xor(s4, 2);
        float lse = m4 + logf(s4);
        *reinterpret_cast<float4*>(out + (size_t)n * 16 + l * 4) =
            make_float4(v0 - lse, v1 - lse, v2 - lse, v3 - lse);
    }
}

// ---------------- host launcher ----------------

extern "C" void kernel_launch(void* const* d_in, const int* in_sizes, int n_in,
                              void* d_out, int out_size, void* d_ws, size_t ws_size,
                              hipStream_t stream) {
    const float* x   = (const float*)d_in[0];
    const int*   ei  = (const int*)d_in[1];
    const float* Wl0 = (const float*)d_in[2];
    const float* bl0 = (const float*)d_in[3];
    const float* Wr0 = (const float*)d_in[4];
    const float* Wl1 = (const float*)d_in[5];
    const float* bl1 = (const float*)d_in[6];
    const float* Wr1 = (const float*)d_in[7];
    const float* Wl2 = (const float*)d_in[8];
    const float* bl2 = (const float*)d_in[9];
    const float* Wr2 = (const float*)d_in[10];
    float* out = (float*)d_out;

    const int* e_src = ei;       // edge_index[0]
    const int* e_dst = ei + NE;  // edge_index[1]

    // workspace carve-out (256B aligned)
    char* ws = (char*)d_ws;
    size_t off = 0;
    auto carve = [&](size_t bytes) -> void* {
        void* p = ws + off;
        off = (off + bytes + 255) & ~(size_t)255;
        return p;
    };
    int*   deg  = (int*)carve((size_t)(NN + 128) * 4);  // deg | hist(32) | cursor(32)
    int*   hist = deg + NN;
    int*   curs = deg + NN + 32;
    int*   cur  = (int*)carve((size_t)NN * 4);
    int*   bsum = (int*)carve(512 * 4);
    int*   col2 = (int*)carve((size_t)(NE + 3 * NN + 64) * 4);  // padded CSR
    int4*  desc = (int4*)carve((size_t)NN * 16);
    u16*   xb   = (u16*)carve((size_t)(NN + 1) * DD * 2);       // +1: zero row
    u16*   H1   = (u16*)carve((size_t)(NN + 1) * DD * 2);       // +1: zero row
    u16*   Wc0  = (u16*)carve((size_t)128 * 256 * 2);
    u16*   Wc1  = (u16*)carve((size_t)128 * 256 * 2);
    u16*   Wc2  = (u16*)carve((size_t)32 * 128 * 2);
    u16*   hl2b = (u16*)carve((size_t)(NN + 1) * 16 * 2);       // +1: zero row
    float* hr2  = (float*)carve((size_t)NN * 16 * 4);
    (void)ws_size; (void)in_sizes; (void)n_in; (void)out_size;

    // setup: zero {deg|hist|cursor}, then sectioned prep
    hipMemsetAsync(deg, 0, (size_t)(NN + 128) * 4, stream);
    k_setup<<<NB_CAST + NB_PREPW + NB_PREPW2 + NB_DEG + 1, 256, 0, stream>>>(
        x, xb, Wl0, Wr0, Wl1, Wr1, Wl2, Wr2, Wc0, Wc1, Wc2, e_dst, deg, H1, hl2b);

    // padded CSR + descriptor (degree-bucketed, heavy-first)
    k_scan1<<<NB_SCAN, 256, 0, stream>>>(deg, bsum, hist);
    k_scan2<<<1, 128, 0, stream>>>(bsum, hist, curs);
    k_scan3<<<NB_SCAN, 256, 0, stream>>>(deg, bsum, cur, col2, curs, desc);
    k_scatter<<<(NE + 255) / 256, 256, 0, stream>>>(e_src, e_dst, cur, col2);

    // layer 0: H1 = relu([gather(xb)|xb]@Wc0 + bl0)
    k_fused_layer<true, false><<<NN / 32, 256, 0, stream>>>(
        xb, col2, desc, Wc0, bl0, H1, nullptr, nullptr, nullptr);

    // layer 1 + fused layer-2 transforms (H2 stays in LDS; hl2b/hr2 out)
    k_fused_layer<false, true><<<NN / 32, 256, 0, stream>>>(
        H1, col2, desc, Wc1, bl1, nullptr, Wc2, hl2b, hr2);

    // layer 2 final: fused mean-gather + log_softmax
    k_l2_final<<<NN / 32, 256, 0, stream>>>(hl2b, hr2, col2, desc, bl2, out);
}